// Round 1
// baseline (3182.722 us; speedup 1.0000x reference)
//
#include <hip/hip_runtime.h>
#include <math.h>

// ---------------------------------------------------------------------------
// FGC_23957327577330 — fp32 reference-accurate implementation (round 0).
// Pipeline:
//   t0    = gelu(bn(conv7x7(small_x)))                 (8,64,96,96)
//   small = up2(t0)                                    (8,64,192,192)
//   diff96= apmp(small,x)+apmp(x,small)                (8,1,96,96)
//   iMap  = sigmoid(up2(in_map)); dMap = sigmoid(up2(diff96))
//   scale = (dil3(iMap)-iMap)+(dil3(dMap)-dMap)+1      (8,1,192,192)
//   fn    = beta*conv3x3(x*scale)                      (8,64,192,192)
//   r1    = gelu(bn(conv3x3([small,fn])))              (8,64,192,192)
//   r2    = gelu(bn(conv3x3(r1)))
//   out0  = gelu(bn(conv3x3(r2)))
//   out1  = conv7x7_64to1(out0)
// ---------------------------------------------------------------------------

#define DI __device__ __forceinline__

DI float gelu_f(float v) { return 0.5f * v * (1.0f + erff(v * 0.70710678118654752f)); }

// ---- weight transpose: W[o][ic][k] -> wT[(ic*KK + k)*Cout + o] -------------
__global__ void transpose_w_k(const float* __restrict__ W, float* __restrict__ wT,
                              int Cout, int Cin, int KK) {
  int i = blockIdx.x * 256 + threadIdx.x;
  int n = Cout * Cin * KK;
  if (i >= n) return;
  int k = i % KK; int t = i / KK; int ic = t % Cin; int o = t / Cin;
  wT[(ic * KK + k) * Cout + o] = W[i];
}

// ---- conv 7x7, 128->64, 96x96, pad 3, fused bias+BN+GELU -------------------
__global__ __launch_bounds__(256) void conv_up_k(
    const float* __restrict__ in,   // (8,128,96,96)
    const float* __restrict__ wT,   // [(ic*49+k)*64 + o]
    const float* __restrict__ bias,
    const float* __restrict__ bg, const float* __restrict__ bb,
    const float* __restrict__ bm, const float* __restrict__ bv,
    float* __restrict__ out)        // (8,64,96,96)
{
  const int H = 96;
  int bi = blockIdx.x;
  int tx = bi % 6; int t2 = bi / 6; int ty = t2 % 6; int b = t2 / 6;
  int x0 = tx * 16, y0 = ty * 16;
  int tid = threadIdx.x;
  int og = tid >> 5, pg = tid & 31;
  int py = pg >> 1, px0 = (pg & 1) * 8;
  int oc0 = og * 8;

  __shared__ __align__(16) float s_in[4][22][24];
  __shared__ __align__(16) float s_w[4 * 49 * 64];

  float acc[8][8];
  #pragma unroll
  for (int o = 0; o < 8; ++o)
    #pragma unroll
    for (int p = 0; p < 8; ++p) acc[o][p] = 0.0f;

  for (int ch0 = 0; ch0 < 128; ch0 += 4) {
    for (int e = tid; e < 4 * 22 * 22; e += 256) {
      int c = e / 484; int r = e % 484; int iy = r / 22; int ix = r % 22;
      int gy = y0 + iy - 3, gx = x0 + ix - 3;
      float v = 0.0f;
      if (gy >= 0 && gy < H && gx >= 0 && gx < H)
        v = in[(((size_t)b * 128 + ch0 + c) * H + gy) * H + gx];
      s_in[c][iy][ix] = v;
    }
    const float* wsrc = wT + ch0 * 49 * 64;
    for (int e = tid; e < 4 * 49 * 64; e += 256) s_w[e] = wsrc[e];
    __syncthreads();

    for (int c = 0; c < 4; ++c) {
      for (int ky = 0; ky < 7; ++ky) {
        float rin[14];
        #pragma unroll
        for (int j = 0; j < 14; ++j) rin[j] = s_in[c][py + ky][px0 + j];
        #pragma unroll
        for (int kx = 0; kx < 7; ++kx) {
          const float* wrow = &s_w[((c * 7 + ky) * 7 + kx) * 64 + oc0];
          float4 wa = *reinterpret_cast<const float4*>(wrow);
          float4 wb = *reinterpret_cast<const float4*>(wrow + 4);
          float wv[8] = {wa.x, wa.y, wa.z, wa.w, wb.x, wb.y, wb.z, wb.w};
          #pragma unroll
          for (int o = 0; o < 8; ++o)
            #pragma unroll
            for (int p = 0; p < 8; ++p)
              acc[o][p] = fmaf(rin[p + kx], wv[o], acc[o][p]);
        }
      }
    }
    __syncthreads();
  }

  #pragma unroll
  for (int o = 0; o < 8; ++o) {
    int oc = oc0 + o;
    float sc = bg[oc] * rsqrtf(bv[oc] + 1e-5f);
    float sh = bb[oc] - bm[oc] * sc;
    float bi_ = bias[oc];
    #pragma unroll
    for (int p = 0; p < 8; ++p) {
      float v = (acc[o][p] + bi_) * sc + sh;
      v = gelu_f(v);
      out[(((size_t)b * 64 + oc) * H + (y0 + py)) * H + (x0 + px0 + p)] = v;
    }
  }
}

// ---- generic 3x3 conv at 192x192, Cout=64, fused options -------------------
template <int CIN, bool TWO_IN, bool SCALE_IN, bool BN_GELU, bool BETA>
__global__ __launch_bounds__(256) void conv3_k(
    const float* __restrict__ inA, const float* __restrict__ inB,
    const float* __restrict__ wT,  // [(ic*9+k)*64 + o]
    const float* __restrict__ bias,
    const float* __restrict__ scale,  // per-pixel (B,H,W) or null
    const float* __restrict__ bg, const float* __restrict__ bb,
    const float* __restrict__ bm, const float* __restrict__ bv,
    const float* __restrict__ betap,
    float* __restrict__ out)
{
  const int H = 192;
  int bi = blockIdx.x;
  int tx = bi % 12; int t2 = bi / 12; int ty = t2 % 12; int b = t2 / 12;
  int x0 = tx * 16, y0 = ty * 16;
  int tid = threadIdx.x;
  int og = tid >> 5, pg = tid & 31;
  int py = pg >> 1, px0 = (pg & 1) * 8;
  int oc0 = og * 8;
  constexpr int CA = TWO_IN ? 64 : CIN;

  __shared__ __align__(16) float s_in[16][18][20];
  __shared__ __align__(16) float s_w[16 * 9 * 64];

  float acc[8][8];
  #pragma unroll
  for (int o = 0; o < 8; ++o)
    #pragma unroll
    for (int p = 0; p < 8; ++p) acc[o][p] = 0.0f;

  for (int ch0 = 0; ch0 < CIN; ch0 += 16) {
    const float* sp = (TWO_IN && ch0 >= 64) ? inB : inA;
    int cb = (TWO_IN && ch0 >= 64) ? ch0 - 64 : ch0;
    for (int e = tid; e < 16 * 18 * 18; e += 256) {
      int c = e / 324; int r = e % 324; int iy = r / 18; int ix = r % 18;
      int gy = y0 + iy - 1, gx = x0 + ix - 1;
      float v = 0.0f;
      if (gy >= 0 && gy < H && gx >= 0 && gx < H) {
        v = sp[(((size_t)b * CA + cb + c) * H + gy) * H + gx];
        if (SCALE_IN) v *= scale[((size_t)b * H + gy) * H + gx];
      }
      s_in[c][iy][ix] = v;
    }
    const float* wsrc = wT + ch0 * 9 * 64;
    for (int e = tid; e < 16 * 9 * 64; e += 256) s_w[e] = wsrc[e];
    __syncthreads();

    for (int c = 0; c < 16; ++c) {
      #pragma unroll
      for (int ky = 0; ky < 3; ++ky) {
        float rin[10];
        #pragma unroll
        for (int j = 0; j < 10; ++j) rin[j] = s_in[c][py + ky][px0 + j];
        #pragma unroll
        for (int kx = 0; kx < 3; ++kx) {
          const float* wrow = &s_w[((c * 3 + ky) * 3 + kx) * 64 + oc0];
          float4 wa = *reinterpret_cast<const float4*>(wrow);
          float4 wb = *reinterpret_cast<const float4*>(wrow + 4);
          float wv[8] = {wa.x, wa.y, wa.z, wa.w, wb.x, wb.y, wb.z, wb.w};
          #pragma unroll
          for (int o = 0; o < 8; ++o)
            #pragma unroll
            for (int p = 0; p < 8; ++p)
              acc[o][p] = fmaf(rin[p + kx], wv[o], acc[o][p]);
        }
      }
    }
    __syncthreads();
  }

  float bmul = 1.0f;
  if (BETA) bmul = betap[0];
  #pragma unroll
  for (int o = 0; o < 8; ++o) {
    int oc = oc0 + o;
    float bi_ = bias[oc];
    float sc = 1.0f, sh = 0.0f;
    if (BN_GELU) {
      sc = bg[oc] * rsqrtf(bv[oc] + 1e-5f);
      sh = bb[oc] - bm[oc] * sc;
    }
    #pragma unroll
    for (int p = 0; p < 8; ++p) {
      float v = acc[o][p] + bi_;
      if (BN_GELU) { v = v * sc + sh; v = gelu_f(v); }
      if (BETA) v *= bmul;
      out[(((size_t)b * 64 + oc) * H + (y0 + py)) * H + (x0 + px0 + p)] = v;
    }
  }
}

// ---- conv 7x7, 64->1, 192x192, pad 3 --------------------------------------
__global__ __launch_bounds__(256) void conv_out_k(
    const float* __restrict__ in,   // (8,64,192,192)
    const float* __restrict__ W,    // (1,64,7,7) contiguous [ic][49]
    const float* __restrict__ bias, // (1,)
    float* __restrict__ out)        // (8,1,192,192)
{
  const int H = 192;
  int bi = blockIdx.x;
  int tx = bi % 12; int t2 = bi / 12; int ty = t2 % 12; int b = t2 / 12;
  int x0 = tx * 16, y0 = ty * 16;
  int tid = threadIdx.x;
  int px = tid & 15, py = tid >> 4;

  __shared__ __align__(16) float s_in[16][22][24];
  __shared__ __align__(16) float s_w[64 * 49];

  for (int e = tid; e < 64 * 49; e += 256) s_w[e] = W[e];

  float acc = 0.0f;
  for (int ch0 = 0; ch0 < 64; ch0 += 16) {
    __syncthreads();  // also orders s_w staging before first compute
    for (int e = tid; e < 16 * 22 * 22; e += 256) {
      int c = e / 484; int r = e % 484; int iy = r / 22; int ix = r % 22;
      int gy = y0 + iy - 3, gx = x0 + ix - 3;
      float v = 0.0f;
      if (gy >= 0 && gy < H && gx >= 0 && gx < H)
        v = in[(((size_t)b * 64 + ch0 + c) * H + gy) * H + gx];
      s_in[c][iy][ix] = v;
    }
    __syncthreads();
    for (int c = 0; c < 16; ++c) {
      #pragma unroll
      for (int ky = 0; ky < 7; ++ky)
        #pragma unroll
        for (int kx = 0; kx < 7; ++kx)
          acc = fmaf(s_in[c][py + ky][px + kx], s_w[(ch0 + c) * 49 + ky * 7 + kx], acc);
    }
  }
  out[((size_t)b * H + (y0 + py)) * H + (x0 + px)] = acc + bias[0];
}

// ---- bilinear up2 (96->192), align_corners=True, optional sigmoid ---------
template <bool SIG>
__global__ void up2_k(const float* __restrict__ in, float* __restrict__ out, int total) {
  int i = blockIdx.x * 256 + threadIdx.x;
  if (i >= total) return;
  int x = i % 192; int y = (i / 192) % 192; int bc = i / (192 * 192);
  const float c95 = 95.0f / 191.0f;
  float sy = y * c95; int y0 = (int)sy; int y1 = min(y0 + 1, 95); float wy = sy - (float)y0;
  float sx = x * c95; int x0 = (int)sx; int x1 = min(x0 + 1, 95); float wx = sx - (float)x0;
  const float* p = in + (size_t)bc * 96 * 96;
  float v00 = p[y0 * 96 + x0], v01 = p[y0 * 96 + x1];
  float v10 = p[y1 * 96 + x0], v11 = p[y1 * 96 + x1];
  float v = (1.0f - wx) * ((1.0f - wy) * v00 + wy * v10) +
            wx * ((1.0f - wy) * v01 + wy * v11);
  if (SIG) v = 1.0f / (1.0f + expf(-v));
  out[i] = v;
}

// ---- diff map: ||avg2(small)-max2(x)||_c + ||avg2(x)-max2(small)||_c ------
__global__ void pools_k(const float* __restrict__ small, const float* __restrict__ x,
                        float* __restrict__ out) {
  int i = blockIdx.x * 256 + threadIdx.x;
  if (i >= 8 * 96 * 96) return;
  int xx = i % 96; int y = (i / 96) % 96; int b = i / (96 * 96);
  float s1 = 0.0f, s2 = 0.0f;
  for (int c = 0; c < 64; ++c) {
    size_t base = (((size_t)b * 64 + c) * 192 + 2 * y) * 192 + 2 * xx;
    float a0 = small[base], a1 = small[base + 1], a2 = small[base + 192], a3 = small[base + 193];
    float b0 = x[base],     b1 = x[base + 1],     b2 = x[base + 192],     b3 = x[base + 193];
    float avgS = 0.25f * (a0 + a1 + a2 + a3);
    float maxS = fmaxf(fmaxf(a0, a1), fmaxf(a2, a3));
    float avgX = 0.25f * (b0 + b1 + b2 + b3);
    float maxX = fmaxf(fmaxf(b0, b1), fmaxf(b2, b3));
    float d1 = avgS - maxX; s1 = fmaf(d1, d1, s1);
    float d2 = avgX - maxS; s2 = fmaf(d2, d2, s2);
  }
  out[i] = sqrtf(s1) + sqrtf(s2);
}

// ---- scale map: (dilate3(iM)-iM) + (dilate3(dM)-dM) + 1 -------------------
__global__ void scale_k(const float* __restrict__ iM, const float* __restrict__ dM,
                        float* __restrict__ out) {
  int i = blockIdx.x * 256 + threadIdx.x;
  if (i >= 8 * 192 * 192) return;
  int x = i % 192; int y = (i / 192) % 192; int b = i / (192 * 192);
  const float* pi = iM + (size_t)b * 192 * 192;
  const float* pd = dM + (size_t)b * 192 * 192;
  float mi = -1e30f, md = -1e30f;
  for (int dy = -1; dy <= 1; ++dy) {
    int yy = y + dy;
    if (yy < 0 || yy >= 192) continue;
    for (int dx = -1; dx <= 1; ++dx) {
      int xx = x + dx;
      if (xx < 0 || xx >= 192) continue;
      mi = fmaxf(mi, pi[yy * 192 + xx]);
      md = fmaxf(md, pd[yy * 192 + xx]);
    }
  }
  out[i] = (mi - pi[y * 192 + x]) + (md - pd[y * 192 + x]) + 1.0f;
}

// ---------------------------------------------------------------------------
extern "C" void kernel_launch(void* const* d_in, const int* in_sizes, int n_in,
                              void* d_out, int out_size, void* d_ws, size_t ws_size,
                              hipStream_t stream) {
  (void)in_sizes; (void)n_in; (void)out_size; (void)ws_size;
  const float* x       = (const float*)d_in[0];
  const float* small_x = (const float*)d_in[1];
  const float* in_map  = (const float*)d_in[2];
  const float* W_up = (const float*)d_in[3];  const float* b_up = (const float*)d_in[4];
  const float* g_up = (const float*)d_in[5];  const float* be_up = (const float*)d_in[6];
  const float* m_up = (const float*)d_in[7];  const float* v_up = (const float*)d_in[8];
  const float* W_c2 = (const float*)d_in[9];  const float* b_c2 = (const float*)d_in[10];
  const float* W_d1 = (const float*)d_in[11]; const float* b_d1 = (const float*)d_in[12];
  const float* g_d1 = (const float*)d_in[13]; const float* be_d1 = (const float*)d_in[14];
  const float* m_d1 = (const float*)d_in[15]; const float* v_d1 = (const float*)d_in[16];
  const float* W_d2 = (const float*)d_in[17]; const float* b_d2 = (const float*)d_in[18];
  const float* g_d2 = (const float*)d_in[19]; const float* be_d2 = (const float*)d_in[20];
  const float* m_d2 = (const float*)d_in[21]; const float* v_d2 = (const float*)d_in[22];
  const float* W_d3 = (const float*)d_in[23]; const float* b_d3 = (const float*)d_in[24];
  const float* g_d3 = (const float*)d_in[25]; const float* be_d3 = (const float*)d_in[26];
  const float* m_d3 = (const float*)d_in[27]; const float* v_d3 = (const float*)d_in[28];
  const float* W_out = (const float*)d_in[29]; const float* b_out = (const float*)d_in[30];
  const float* beta = (const float*)d_in[31];

  const size_t SZ = 18874368;  // 8*64*192*192
  float* ws = (float*)d_ws;
  float* small = ws;            // SZ
  float* fn    = ws + SZ;       // SZ  (later reused as r2)
  float* r1    = ws + 2 * SZ;   // SZ  (t0 aliases this region before r1 is live)
  float* t0    = r1;            // 8*64*96*96 = 4,718,592 < SZ
  float* ext   = ws + 3 * SZ;
  float* diff96 = ext;                 // 73728
  float* iMap   = diff96 + 73728;      // 294912
  float* dMap   = iMap + 294912;       // 294912
  float* scaleM = dMap + 294912;       // 294912
  float* wT_up  = scaleM + 294912;     // 401408
  float* wT_c2  = wT_up + 401408;      // 36864
  float* wT_d1  = wT_c2 + 36864;       // 73728
  float* wT_d2  = wT_d1 + 73728;       // 36864
  float* wT_d3  = wT_d2 + 36864;       // 36864
  float* r2 = fn;  // fn dead after conv_d1

  float* out0 = (float*)d_out;         // r   (8,64,192,192)
  float* out1 = out0 + SZ;             // map (8,1,192,192)

  // weight transposes
  transpose_w_k<<<(401408 + 255) / 256, 256, 0, stream>>>(W_up, wT_up, 64, 128, 49);
  transpose_w_k<<<(36864 + 255) / 256, 256, 0, stream>>>(W_c2, wT_c2, 64, 64, 9);
  transpose_w_k<<<(73728 + 255) / 256, 256, 0, stream>>>(W_d1, wT_d1, 64, 128, 9);
  transpose_w_k<<<(36864 + 255) / 256, 256, 0, stream>>>(W_d2, wT_d2, 64, 64, 9);
  transpose_w_k<<<(36864 + 255) / 256, 256, 0, stream>>>(W_d3, wT_d3, 64, 64, 9);

  // up path
  conv_up_k<<<288, 256, 0, stream>>>(small_x, wT_up, b_up, g_up, be_up, m_up, v_up, t0);
  up2_k<false><<<(int)(SZ / 256), 256, 0, stream>>>(t0, small, (int)SZ);

  // uncertainty maps
  pools_k<<<288, 256, 0, stream>>>(small, x, diff96);
  up2_k<true><<<1152, 256, 0, stream>>>(in_map, iMap, 8 * 192 * 192);
  up2_k<true><<<1152, 256, 0, stream>>>(diff96, dMap, 8 * 192 * 192);
  scale_k<<<1152, 256, 0, stream>>>(iMap, dMap, scaleM);

  // conv chain
  conv3_k<64, false, true, false, true><<<1152, 256, 0, stream>>>(
      x, nullptr, wT_c2, b_c2, scaleM, nullptr, nullptr, nullptr, nullptr, beta, fn);
  conv3_k<128, true, false, true, false><<<1152, 256, 0, stream>>>(
      small, fn, wT_d1, b_d1, nullptr, g_d1, be_d1, m_d1, v_d1, nullptr, r1);
  conv3_k<64, false, false, true, false><<<1152, 256, 0, stream>>>(
      r1, nullptr, wT_d2, b_d2, nullptr, g_d2, be_d2, m_d2, v_d2, nullptr, r2);
  conv3_k<64, false, false, true, false><<<1152, 256, 0, stream>>>(
      r2, nullptr, wT_d3, b_d3, nullptr, g_d3, be_d3, m_d3, v_d3, nullptr, out0);

  conv_out_k<<<1152, 256, 0, stream>>>(out0, W_out, b_out, out1);
}

// Round 2
// 968.251 us; speedup vs baseline: 3.2871x; 3.2871x over previous
//
#include <hip/hip_runtime.h>
#include <math.h>

// ---------------------------------------------------------------------------
// FGC_23957327577330 — round 2: bf16 MFMA implicit-GEMM convs.
//   All multi-channel convs use mfma_f32_16x16x32_bf16.
//   A (input) staged channels-last bf16 in LDS -> ds_read_b128 fragments.
//   B (weights) precomputed to per-lane fragment layout in global (L2-hot).
//   conv_up split-K over 4 ic-passes (occupancy fix) + fused reduce epilogue.
// ---------------------------------------------------------------------------

#define DI __device__ __forceinline__

typedef __attribute__((ext_vector_type(8))) short short8;
typedef __attribute__((ext_vector_type(4))) float floatx4;

DI float gelu_f(float v) { return 0.5f * v * (1.0f + erff(v * 0.70710678118654752f)); }

DI unsigned short f2b(float f) {          // fp32 -> bf16 bits, round-to-nearest-even
  unsigned u = __float_as_uint(f);
  u += 0x7FFFu + ((u >> 16) & 1u);
  return (unsigned short)(u >> 16);
}
DI unsigned pack2(float a, float b) {
  return (unsigned)f2b(a) | ((unsigned)f2b(b) << 16);
}

// ---- B-fragment precompute, 3x3 convs: 18 ksteps (64 ic) -------------------
// wf[((s*4+nt)*64+lane)*8+j] = bf16( W[oc][ic][ky][kx] )
//   s: tap*2+ich, ic = icg0 + ich*32 + (lane>>4)*8 + j, oc = nt*16 + (lane&15)
__global__ void frag3_k(const float* __restrict__ W, short* __restrict__ wf,
                        int CIN, int icg0) {
  int i = blockIdx.x * 256 + threadIdx.x;
  if (i >= 18 * 4 * 64 * 8) return;
  int j = i & 7; int lane = (i >> 3) & 63; int nt = (i >> 9) & 3; int s = i >> 11;
  int q = lane >> 4, r16 = lane & 15;
  int tap = s >> 1, ich = s & 1;
  int ky = tap / 3, kx = tap % 3;
  int ic = icg0 + ich * 32 + q * 8 + j;
  int oc = nt * 16 + r16;
  wf[i] = (short)f2b(W[((oc * CIN + ic) * 3 + ky) * 3 + kx]);
}

// ---- B-fragment precompute, conv_up 7x7 128->64: 196 ksteps ---------------
__global__ void frag_up_k(const float* __restrict__ W, short* __restrict__ wf) {
  int i = blockIdx.x * 256 + threadIdx.x;
  if (i >= 196 * 4 * 64 * 8) return;
  int j = i & 7; int lane = (i >> 3) & 63; int nt = (i >> 9) & 3; int s = i >> 11;
  int q = lane >> 4, r16 = lane & 15;
  int pass = s / 49, tap = s % 49;
  int ky = tap / 7, kx = tap % 7;
  int ic = pass * 32 + q * 8 + j;
  int oc = nt * 16 + r16;
  wf[i] = (short)f2b(W[((oc * 128 + ic) * 7 + ky) * 7 + kx]);
}

// ---- MFMA 3x3 conv at 192x192, Cin=64 per half, Cout=64 --------------------
template <bool TWO_IN, bool SCALE_IN, bool BN_GELU, bool BETA>
__global__ __launch_bounds__(256) void conv3m_k(
    const float* __restrict__ inA, const float* __restrict__ inB,
    const short* __restrict__ wfrag,
    const float* __restrict__ bias, const float* __restrict__ scale,
    const float* __restrict__ bg, const float* __restrict__ bb,
    const float* __restrict__ bm, const float* __restrict__ bv,
    const float* __restrict__ betap, float* __restrict__ out)
{
  const int H = 192;
  int bi = blockIdx.x;
  int tx = bi % 12, t2 = bi / 12, ty = t2 % 12, b = t2 / 12;
  int x0 = tx * 16, y0 = ty * 16;
  int tid = threadIdx.x;
  int w = tid >> 6, lane = tid & 63, q = lane >> 4, r16 = lane & 15;

  // channels-last bf16 tile, ic-stride 72 (16B-aligned rows, bank-spread)
  __shared__ short s_in[18 * 18 * 72];
  const short8* wf = (const short8*)wfrag;

  floatx4 acc[4][4];
  #pragma unroll
  for (int a = 0; a < 4; ++a)
    #pragma unroll
    for (int c = 0; c < 4; ++c) acc[a][c] = (floatx4){0.f, 0.f, 0.f, 0.f};

  const int HALVES = TWO_IN ? 2 : 1;
  for (int half = 0; half < HALVES; ++half) {
    const float* src = half ? inB : inA;
    if (half) __syncthreads();
    for (int e = tid; e < 16 * 18 * 18; e += 256) {
      int cg = e / 324, rr = e % 324, yy = rr / 18, xx = rr % 18;
      int gy = y0 + yy - 1, gx = x0 + xx - 1;
      float v0 = 0.f, v1 = 0.f, v2 = 0.f, v3 = 0.f;
      if (gy >= 0 && gy < H && gx >= 0 && gx < H) {
        size_t base = (((size_t)b * 64 + cg * 4) * H + gy) * H + gx;
        v0 = src[base];
        v1 = src[base + 36864];
        v2 = src[base + 73728];
        v3 = src[base + 110592];
        if (SCALE_IN) {
          float sc = scale[((size_t)b * H + gy) * H + gx];
          v0 *= sc; v1 *= sc; v2 *= sc; v3 *= sc;
        }
      }
      *reinterpret_cast<int2*>(&s_in[(yy * 18 + xx) * 72 + cg * 4]) =
          make_int2(pack2(v0, v1), pack2(v2, v3));
    }
    __syncthreads();

    #pragma unroll 1
    for (int s = 0; s < 18; ++s) {
      int tap = s >> 1, ich = s & 1;
      int ky = tap / 3, kx = tap - ky * 3;
      int sg = half * 18 + s;
      short8 bfr[4];
      #pragma unroll
      for (int nt = 0; nt < 4; ++nt) bfr[nt] = wf[(sg * 4 + nt) * 64 + lane];
      #pragma unroll
      for (int mt = 0; mt < 4; ++mt) {
        int iy = w * 4 + mt + ky;
        int ix = r16 + kx;
        short8 afr = *reinterpret_cast<const short8*>(
            &s_in[(iy * 18 + ix) * 72 + ich * 32 + q * 8]);
        #pragma unroll
        for (int nt = 0; nt < 4; ++nt)
          acc[mt][nt] = __builtin_amdgcn_mfma_f32_16x16x32_bf16(afr, bfr[nt], acc[mt][nt], 0, 0, 0);
      }
    }
  }

  float bmul = BETA ? betap[0] : 1.0f;
  #pragma unroll
  for (int mt = 0; mt < 4; ++mt) {
    int gy = y0 + w * 4 + mt;
    #pragma unroll
    for (int nt = 0; nt < 4; ++nt) {
      int oc = nt * 16 + r16;
      float bi_ = bias[oc];
      float sc = 1.f, sh = 0.f;
      if (BN_GELU) { sc = bg[oc] * rsqrtf(bv[oc] + 1e-5f); sh = bb[oc] - bm[oc] * sc; }
      float4 o;
      float* op = &o.x;
      #pragma unroll
      for (int rg = 0; rg < 4; ++rg) {
        float v = acc[mt][nt][rg] + bi_;
        if (BN_GELU) { v = v * sc + sh; v = gelu_f(v); }
        if (BETA) v *= bmul;
        op[rg] = v;
      }
      *reinterpret_cast<float4*>(&out[(((size_t)b * 64 + oc) * H + gy) * H + x0 + q * 4]) = o;
    }
  }
}

// ---- MFMA conv_up 7x7 128->64 @96x96, split-K (4 ic-passes), fp32 partials -
__global__ __launch_bounds__(256) void conv_up_m_k(
    const float* __restrict__ in, const short* __restrict__ wfrag,
    float* __restrict__ part)
{
  const int H = 96;
  int bi = blockIdx.x;
  int pass = bi & 3; int tile = bi >> 2;
  int tx = tile % 6, t2 = tile / 6, ty = t2 % 6, b = t2 / 6;
  int x0 = tx * 16, y0 = ty * 16;
  int tid = threadIdx.x;
  int w = tid >> 6, lane = tid & 63, q = lane >> 4, r16 = lane & 15;

  __shared__ short s_in[22 * 22 * 40];  // 32 ic + pad, stride 40
  const short8* wf = (const short8*)wfrag;

  floatx4 acc[4][4];
  #pragma unroll
  for (int a = 0; a < 4; ++a)
    #pragma unroll
    for (int c = 0; c < 4; ++c) acc[a][c] = (floatx4){0.f, 0.f, 0.f, 0.f};

  for (int e = tid; e < 8 * 22 * 22; e += 256) {
    int cg = e / 484, rr = e % 484, yy = rr / 22, xx = rr % 22;
    int gy = y0 + yy - 3, gx = x0 + xx - 3;
    float v0 = 0.f, v1 = 0.f, v2 = 0.f, v3 = 0.f;
    if (gy >= 0 && gy < H && gx >= 0 && gx < H) {
      size_t base = (((size_t)b * 128 + pass * 32 + cg * 4) * H + gy) * H + gx;
      v0 = in[base];
      v1 = in[base + 9216];
      v2 = in[base + 18432];
      v3 = in[base + 27648];
    }
    *reinterpret_cast<int2*>(&s_in[(yy * 22 + xx) * 40 + cg * 4]) =
        make_int2(pack2(v0, v1), pack2(v2, v3));
  }
  __syncthreads();

  #pragma unroll 1
  for (int s = 0; s < 49; ++s) {
    int ky = s / 7, kx = s - ky * 7;
    short8 bfr[4];
    #pragma unroll
    for (int nt = 0; nt < 4; ++nt) bfr[nt] = wf[((pass * 49 + s) * 4 + nt) * 64 + lane];
    #pragma unroll
    for (int mt = 0; mt < 4; ++mt) {
      int iy = w * 4 + mt + ky;
      int ix = r16 + kx;
      short8 afr = *reinterpret_cast<const short8*>(&s_in[(iy * 22 + ix) * 40 + q * 8]);
      #pragma unroll
      for (int nt = 0; nt < 4; ++nt)
        acc[mt][nt] = __builtin_amdgcn_mfma_f32_16x16x32_bf16(afr, bfr[nt], acc[mt][nt], 0, 0, 0);
    }
  }

  float* dst = part + (size_t)pass * 4718592;
  #pragma unroll
  for (int mt = 0; mt < 4; ++mt) {
    int gy = y0 + w * 4 + mt;
    #pragma unroll
    for (int nt = 0; nt < 4; ++nt) {
      int oc = nt * 16 + r16;
      float4 o;
      o.x = acc[mt][nt][0]; o.y = acc[mt][nt][1];
      o.z = acc[mt][nt][2]; o.w = acc[mt][nt][3];
      *reinterpret_cast<float4*>(&dst[(((size_t)b * 64 + oc) * H + gy) * H + x0 + q * 4]) = o;
    }
  }
}

// ---- reduce 4 partials + bias + BN + GELU -> t0 ---------------------------
__global__ void reduce_up_k(const float* __restrict__ part,
    const float* __restrict__ bias,
    const float* __restrict__ bg, const float* __restrict__ bb,
    const float* __restrict__ bm, const float* __restrict__ bv,
    float* __restrict__ out)
{
  int i4 = blockIdx.x * 256 + threadIdx.x;
  if (i4 >= 1179648) return;
  size_t i = (size_t)i4 * 4;
  const size_t N = 4718592;
  float4 a0 = *reinterpret_cast<const float4*>(part + i);
  float4 a1 = *reinterpret_cast<const float4*>(part + N + i);
  float4 a2 = *reinterpret_cast<const float4*>(part + 2 * N + i);
  float4 a3 = *reinterpret_cast<const float4*>(part + 3 * N + i);
  int oc = (int)((i / 9216) & 63);
  float sc = bg[oc] * rsqrtf(bv[oc] + 1e-5f);
  float sh = bb[oc] - bm[oc] * sc;
  float bi_ = bias[oc];
  float4 o;
  o.x = gelu_f((a0.x + a1.x + a2.x + a3.x + bi_) * sc + sh);
  o.y = gelu_f((a0.y + a1.y + a2.y + a3.y + bi_) * sc + sh);
  o.z = gelu_f((a0.z + a1.z + a2.z + a3.z + bi_) * sc + sh);
  o.w = gelu_f((a0.w + a1.w + a2.w + a3.w + bi_) * sc + sh);
  *reinterpret_cast<float4*>(out + i) = o;
}

// ---- conv 7x7, 64->1, 192x192, pad 3 (fp32 VALU) ---------------------------
__global__ __launch_bounds__(256) void conv_out_k(
    const float* __restrict__ in, const float* __restrict__ W,
    const float* __restrict__ bias, float* __restrict__ out)
{
  const int H = 192;
  int bi = blockIdx.x;
  int tx = bi % 12; int t2 = bi / 12; int ty = t2 % 12; int b = t2 / 12;
  int x0 = tx * 16, y0 = ty * 16;
  int tid = threadIdx.x;
  int px = tid & 15, py = tid >> 4;

  __shared__ __align__(16) float s_in[16][22][24];
  __shared__ __align__(16) float s_w[64 * 49];

  for (int e = tid; e < 64 * 49; e += 256) s_w[e] = W[e];

  float acc = 0.0f;
  for (int ch0 = 0; ch0 < 64; ch0 += 16) {
    __syncthreads();
    for (int e = tid; e < 16 * 22 * 22; e += 256) {
      int c = e / 484; int r = e % 484; int iy = r / 22; int ix = r % 22;
      int gy = y0 + iy - 3, gx = x0 + ix - 3;
      float v = 0.0f;
      if (gy >= 0 && gy < H && gx >= 0 && gx < H)
        v = in[(((size_t)b * 64 + ch0 + c) * H + gy) * H + gx];
      s_in[c][iy][ix] = v;
    }
    __syncthreads();
    for (int c = 0; c < 16; ++c) {
      #pragma unroll
      for (int ky = 0; ky < 7; ++ky)
        #pragma unroll
        for (int kx = 0; kx < 7; ++kx)
          acc = fmaf(s_in[c][py + ky][px + kx], s_w[(ch0 + c) * 49 + ky * 7 + kx], acc);
    }
  }
  out[((size_t)b * H + (y0 + py)) * H + (x0 + px)] = acc + bias[0];
}

// ---- bilinear up2 (96->192), align_corners=True, optional sigmoid ---------
template <bool SIG>
__global__ void up2_k(const float* __restrict__ in, float* __restrict__ out, int total) {
  int i = blockIdx.x * 256 + threadIdx.x;
  if (i >= total) return;
  int x = i % 192; int y = (i / 192) % 192; int bc = i / (192 * 192);
  const float c95 = 95.0f / 191.0f;
  float sy = y * c95; int y0 = (int)sy; int y1 = min(y0 + 1, 95); float wy = sy - (float)y0;
  float sx = x * c95; int x0 = (int)sx; int x1 = min(x0 + 1, 95); float wx = sx - (float)x0;
  const float* p = in + (size_t)bc * 96 * 96;
  float v00 = p[y0 * 96 + x0], v01 = p[y0 * 96 + x1];
  float v10 = p[y1 * 96 + x0], v11 = p[y1 * 96 + x1];
  float v = (1.0f - wx) * ((1.0f - wy) * v00 + wy * v10) +
            wx * ((1.0f - wy) * v01 + wy * v11);
  if (SIG) v = 1.0f / (1.0f + expf(-v));
  out[i] = v;
}

// ---- diff map: ||avg2(small)-max2(x)||_c + ||avg2(x)-max2(small)||_c ------
__global__ void pools_k(const float* __restrict__ small, const float* __restrict__ x,
                        float* __restrict__ out) {
  int i = blockIdx.x * 256 + threadIdx.x;
  if (i >= 8 * 96 * 96) return;
  int xx = i % 96; int y = (i / 96) % 96; int b = i / (96 * 96);
  float s1 = 0.0f, s2 = 0.0f;
  for (int c = 0; c < 64; ++c) {
    size_t base = (((size_t)b * 64 + c) * 192 + 2 * y) * 192 + 2 * xx;
    float a0 = small[base], a1 = small[base + 1], a2 = small[base + 192], a3 = small[base + 193];
    float b0 = x[base],     b1 = x[base + 1],     b2 = x[base + 192],     b3 = x[base + 193];
    float avgS = 0.25f * (a0 + a1 + a2 + a3);
    float maxS = fmaxf(fmaxf(a0, a1), fmaxf(a2, a3));
    float avgX = 0.25f * (b0 + b1 + b2 + b3);
    float maxX = fmaxf(fmaxf(b0, b1), fmaxf(b2, b3));
    float d1 = avgS - maxX; s1 = fmaf(d1, d1, s1);
    float d2 = avgX - maxS; s2 = fmaf(d2, d2, s2);
  }
  out[i] = sqrtf(s1) + sqrtf(s2);
}

// ---- scale map: (dilate3(iM)-iM) + (dilate3(dM)-dM) + 1 -------------------
__global__ void scale_k(const float* __restrict__ iM, const float* __restrict__ dM,
                        float* __restrict__ out) {
  int i = blockIdx.x * 256 + threadIdx.x;
  if (i >= 8 * 192 * 192) return;
  int x = i % 192; int y = (i / 192) % 192; int b = i / (192 * 192);
  const float* pi = iM + (size_t)b * 192 * 192;
  const float* pd = dM + (size_t)b * 192 * 192;
  float mi = -1e30f, md = -1e30f;
  for (int dy = -1; dy <= 1; ++dy) {
    int yy = y + dy;
    if (yy < 0 || yy >= 192) continue;
    for (int dx = -1; dx <= 1; ++dx) {
      int xx = x + dx;
      if (xx < 0 || xx >= 192) continue;
      mi = fmaxf(mi, pi[yy * 192 + xx]);
      md = fmaxf(md, pd[yy * 192 + xx]);
    }
  }
  out[i] = (mi - pi[y * 192 + x]) + (md - pd[y * 192 + x]) + 1.0f;
}

// ---------------------------------------------------------------------------
extern "C" void kernel_launch(void* const* d_in, const int* in_sizes, int n_in,
                              void* d_out, int out_size, void* d_ws, size_t ws_size,
                              hipStream_t stream) {
  (void)in_sizes; (void)n_in; (void)out_size; (void)ws_size;
  const float* x       = (const float*)d_in[0];
  const float* small_x = (const float*)d_in[1];
  const float* in_map  = (const float*)d_in[2];
  const float* W_up = (const float*)d_in[3];  const float* b_up = (const float*)d_in[4];
  const float* g_up = (const float*)d_in[5];  const float* be_up = (const float*)d_in[6];
  const float* m_up = (const float*)d_in[7];  const float* v_up = (const float*)d_in[8];
  const float* W_c2 = (const float*)d_in[9];  const float* b_c2 = (const float*)d_in[10];
  const float* W_d1 = (const float*)d_in[11]; const float* b_d1 = (const float*)d_in[12];
  const float* g_d1 = (const float*)d_in[13]; const float* be_d1 = (const float*)d_in[14];
  const float* m_d1 = (const float*)d_in[15]; const float* v_d1 = (const float*)d_in[16];
  const float* W_d2 = (const float*)d_in[17]; const float* b_d2 = (const float*)d_in[18];
  const float* g_d2 = (const float*)d_in[19]; const float* be_d2 = (const float*)d_in[20];
  const float* m_d2 = (const float*)d_in[21]; const float* v_d2 = (const float*)d_in[22];
  const float* W_d3 = (const float*)d_in[23]; const float* b_d3 = (const float*)d_in[24];
  const float* g_d3 = (const float*)d_in[25]; const float* be_d3 = (const float*)d_in[26];
  const float* m_d3 = (const float*)d_in[27]; const float* v_d3 = (const float*)d_in[28];
  const float* W_out = (const float*)d_in[29]; const float* b_out = (const float*)d_in[30];
  const float* beta = (const float*)d_in[31];

  const size_t SZ = 18874368;  // 8*64*192*192
  float* ws = (float*)d_ws;
  float* small = ws;            // SZ
  float* fn    = ws + SZ;       // SZ ; also split-K partial buffer (4*4718592 == SZ)
  float* part  = fn;
  float* r1    = ws + 2 * SZ;   // SZ ; t0 aliases front
  float* t0    = r1;            // 4718592 floats
  float* r2    = fn;            // fn dead after conv_d1
  float* ext   = ws + 3 * SZ;
  float* diff96 = ext;                 // 73728
  float* iMap   = diff96 + 73728;      // 294912
  float* dMap   = iMap + 294912;       // 294912
  float* scaleM = dMap + 294912;       // 294912
  short* wf_up = (short*)(scaleM + 294912);  // 401408 shorts (16B-aligned)
  short* wf_c2 = wf_up + 401408;             // 36864
  short* wf_d1 = wf_c2 + 36864;              // 73728 (two 64-ic halves)
  short* wf_d2 = wf_d1 + 73728;              // 36864
  short* wf_d3 = wf_d2 + 36864;              // 36864

  float* out0 = (float*)d_out;         // r   (8,64,192,192)
  float* out1 = out0 + SZ;             // map (8,1,192,192)

  // B-fragment precompute
  frag_up_k<<<1568, 256, 0, stream>>>(W_up, wf_up);
  frag3_k<<<144, 256, 0, stream>>>(W_c2, wf_c2, 64, 0);
  frag3_k<<<144, 256, 0, stream>>>(W_d1, wf_d1, 128, 0);
  frag3_k<<<144, 256, 0, stream>>>(W_d1, wf_d1 + 36864, 128, 64);
  frag3_k<<<144, 256, 0, stream>>>(W_d2, wf_d2, 64, 0);
  frag3_k<<<144, 256, 0, stream>>>(W_d3, wf_d3, 64, 0);

  // up path: split-K MFMA conv + fused reduce/BN/GELU, then bilinear up2
  conv_up_m_k<<<1152, 256, 0, stream>>>(small_x, wf_up, part);
  reduce_up_k<<<4608, 256, 0, stream>>>(part, b_up, g_up, be_up, m_up, v_up, t0);
  up2_k<false><<<(int)(SZ / 256), 256, 0, stream>>>(t0, small, (int)SZ);

  // uncertainty maps
  pools_k<<<288, 256, 0, stream>>>(small, x, diff96);
  up2_k<true><<<1152, 256, 0, stream>>>(in_map, iMap, 8 * 192 * 192);
  up2_k<true><<<1152, 256, 0, stream>>>(diff96, dMap, 8 * 192 * 192);
  scale_k<<<1152, 256, 0, stream>>>(iMap, dMap, scaleM);

  // conv chain (MFMA)
  conv3m_k<false, true, false, true><<<1152, 256, 0, stream>>>(
      x, nullptr, wf_c2, b_c2, scaleM, nullptr, nullptr, nullptr, nullptr, beta, fn);
  conv3m_k<true, false, true, false><<<1152, 256, 0, stream>>>(
      small, fn, wf_d1, b_d1, nullptr, g_d1, be_d1, m_d1, v_d1, nullptr, r1);
  conv3m_k<false, false, true, false><<<1152, 256, 0, stream>>>(
      r1, nullptr, wf_d2, b_d2, nullptr, g_d2, be_d2, m_d2, v_d2, nullptr, r2);
  conv3m_k<false, false, true, false><<<1152, 256, 0, stream>>>(
      r2, nullptr, wf_d3, b_d3, nullptr, g_d3, be_d3, m_d3, v_d3, nullptr, out0);

  conv_out_k<<<1152, 256, 0, stream>>>(out0, W_out, b_out, out1);
}

// Round 3
// 935.014 us; speedup vs baseline: 3.4039x; 1.0355x over previous
//
#include <hip/hip_runtime.h>
#include <math.h>

// ---------------------------------------------------------------------------
// FGC_23957327577330 — round 3: bf16 MFMA convs + register-blocked conv_out.
//   conv_out: 4-row x 4-col register blocking, 16 ch-groups split-K,
//             uniform scalar weight loads, fp32 partials + reduce.
//   pools_k: float4 vectorized (2 outputs/thread).
// ---------------------------------------------------------------------------

#define DI __device__ __forceinline__

typedef __attribute__((ext_vector_type(8))) short short8;
typedef __attribute__((ext_vector_type(4))) float floatx4;

DI float gelu_f(float v) { return 0.5f * v * (1.0f + erff(v * 0.70710678118654752f)); }

DI unsigned short f2b(float f) {          // fp32 -> bf16 bits, round-to-nearest-even
  unsigned u = __float_as_uint(f);
  u += 0x7FFFu + ((u >> 16) & 1u);
  return (unsigned short)(u >> 16);
}
DI unsigned pack2(float a, float b) {
  return (unsigned)f2b(a) | ((unsigned)f2b(b) << 16);
}

// ---- B-fragment precompute, 3x3 convs: 18 ksteps (64 ic) -------------------
__global__ void frag3_k(const float* __restrict__ W, short* __restrict__ wf,
                        int CIN, int icg0) {
  int i = blockIdx.x * 256 + threadIdx.x;
  if (i >= 18 * 4 * 64 * 8) return;
  int j = i & 7; int lane = (i >> 3) & 63; int nt = (i >> 9) & 3; int s = i >> 11;
  int q = lane >> 4, r16 = lane & 15;
  int tap = s >> 1, ich = s & 1;
  int ky = tap / 3, kx = tap % 3;
  int ic = icg0 + ich * 32 + q * 8 + j;
  int oc = nt * 16 + r16;
  wf[i] = (short)f2b(W[((oc * CIN + ic) * 3 + ky) * 3 + kx]);
}

// ---- B-fragment precompute, conv_up 7x7 128->64: 196 ksteps ---------------
__global__ void frag_up_k(const float* __restrict__ W, short* __restrict__ wf) {
  int i = blockIdx.x * 256 + threadIdx.x;
  if (i >= 196 * 4 * 64 * 8) return;
  int j = i & 7; int lane = (i >> 3) & 63; int nt = (i >> 9) & 3; int s = i >> 11;
  int q = lane >> 4, r16 = lane & 15;
  int pass = s / 49, tap = s % 49;
  int ky = tap / 7, kx = tap % 7;
  int ic = pass * 32 + q * 8 + j;
  int oc = nt * 16 + r16;
  wf[i] = (short)f2b(W[((oc * 128 + ic) * 7 + ky) * 7 + kx]);
}

// ---- MFMA 3x3 conv at 192x192, Cin=64 per half, Cout=64 --------------------
template <bool TWO_IN, bool SCALE_IN, bool BN_GELU, bool BETA>
__global__ __launch_bounds__(256) void conv3m_k(
    const float* __restrict__ inA, const float* __restrict__ inB,
    const short* __restrict__ wfrag,
    const float* __restrict__ bias, const float* __restrict__ scale,
    const float* __restrict__ bg, const float* __restrict__ bb,
    const float* __restrict__ bm, const float* __restrict__ bv,
    const float* __restrict__ betap, float* __restrict__ out)
{
  const int H = 192;
  int bi = blockIdx.x;
  int tx = bi % 12, t2 = bi / 12, ty = t2 % 12, b = t2 / 12;
  int x0 = tx * 16, y0 = ty * 16;
  int tid = threadIdx.x;
  int w = tid >> 6, lane = tid & 63, q = lane >> 4, r16 = lane & 15;

  __shared__ short s_in[18 * 18 * 72];
  const short8* wf = (const short8*)wfrag;

  floatx4 acc[4][4];
  #pragma unroll
  for (int a = 0; a < 4; ++a)
    #pragma unroll
    for (int c = 0; c < 4; ++c) acc[a][c] = (floatx4){0.f, 0.f, 0.f, 0.f};

  const int HALVES = TWO_IN ? 2 : 1;
  for (int half = 0; half < HALVES; ++half) {
    const float* src = half ? inB : inA;
    if (half) __syncthreads();
    for (int e = tid; e < 16 * 18 * 18; e += 256) {
      int cg = e / 324, rr = e % 324, yy = rr / 18, xx = rr % 18;
      int gy = y0 + yy - 1, gx = x0 + xx - 1;
      float v0 = 0.f, v1 = 0.f, v2 = 0.f, v3 = 0.f;
      if (gy >= 0 && gy < H && gx >= 0 && gx < H) {
        size_t base = (((size_t)b * 64 + cg * 4) * H + gy) * H + gx;
        v0 = src[base];
        v1 = src[base + 36864];
        v2 = src[base + 73728];
        v3 = src[base + 110592];
        if (SCALE_IN) {
          float sc = scale[((size_t)b * H + gy) * H + gx];
          v0 *= sc; v1 *= sc; v2 *= sc; v3 *= sc;
        }
      }
      *reinterpret_cast<int2*>(&s_in[(yy * 18 + xx) * 72 + cg * 4]) =
          make_int2(pack2(v0, v1), pack2(v2, v3));
    }
    __syncthreads();

    #pragma unroll 1
    for (int s = 0; s < 18; ++s) {
      int tap = s >> 1, ich = s & 1;
      int ky = tap / 3, kx = tap - ky * 3;
      int sg = half * 18 + s;
      short8 bfr[4];
      #pragma unroll
      for (int nt = 0; nt < 4; ++nt) bfr[nt] = wf[(sg * 4 + nt) * 64 + lane];
      #pragma unroll
      for (int mt = 0; mt < 4; ++mt) {
        int iy = w * 4 + mt + ky;
        int ix = r16 + kx;
        short8 afr = *reinterpret_cast<const short8*>(
            &s_in[(iy * 18 + ix) * 72 + ich * 32 + q * 8]);
        #pragma unroll
        for (int nt = 0; nt < 4; ++nt)
          acc[mt][nt] = __builtin_amdgcn_mfma_f32_16x16x32_bf16(afr, bfr[nt], acc[mt][nt], 0, 0, 0);
      }
    }
  }

  float bmul = BETA ? betap[0] : 1.0f;
  #pragma unroll
  for (int mt = 0; mt < 4; ++mt) {
    int gy = y0 + w * 4 + mt;
    #pragma unroll
    for (int nt = 0; nt < 4; ++nt) {
      int oc = nt * 16 + r16;
      float bi_ = bias[oc];
      float sc = 1.f, sh = 0.f;
      if (BN_GELU) { sc = bg[oc] * rsqrtf(bv[oc] + 1e-5f); sh = bb[oc] - bm[oc] * sc; }
      float4 o;
      float* op = &o.x;
      #pragma unroll
      for (int rg = 0; rg < 4; ++rg) {
        float v = acc[mt][nt][rg] + bi_;
        if (BN_GELU) { v = v * sc + sh; v = gelu_f(v); }
        if (BETA) v *= bmul;
        op[rg] = v;
      }
      *reinterpret_cast<float4*>(&out[(((size_t)b * 64 + oc) * H + gy) * H + x0 + q * 4]) = o;
    }
  }
}

// ---- MFMA conv_up 7x7 128->64 @96x96, split-K (4 ic-passes), fp32 partials -
__global__ __launch_bounds__(256) void conv_up_m_k(
    const float* __restrict__ in, const short* __restrict__ wfrag,
    float* __restrict__ part)
{
  const int H = 96;
  int bi = blockIdx.x;
  int pass = bi & 3; int tile = bi >> 2;
  int tx = tile % 6, t2 = tile / 6, ty = t2 % 6, b = t2 / 6;
  int x0 = tx * 16, y0 = ty * 16;
  int tid = threadIdx.x;
  int w = tid >> 6, lane = tid & 63, q = lane >> 4, r16 = lane & 15;

  __shared__ short s_in[22 * 22 * 40];
  const short8* wf = (const short8*)wfrag;

  floatx4 acc[4][4];
  #pragma unroll
  for (int a = 0; a < 4; ++a)
    #pragma unroll
    for (int c = 0; c < 4; ++c) acc[a][c] = (floatx4){0.f, 0.f, 0.f, 0.f};

  for (int e = tid; e < 8 * 22 * 22; e += 256) {
    int cg = e / 484, rr = e % 484, yy = rr / 22, xx = rr % 22;
    int gy = y0 + yy - 3, gx = x0 + xx - 3;
    float v0 = 0.f, v1 = 0.f, v2 = 0.f, v3 = 0.f;
    if (gy >= 0 && gy < H && gx >= 0 && gx < H) {
      size_t base = (((size_t)b * 128 + pass * 32 + cg * 4) * H + gy) * H + gx;
      v0 = in[base];
      v1 = in[base + 9216];
      v2 = in[base + 18432];
      v3 = in[base + 27648];
    }
    *reinterpret_cast<int2*>(&s_in[(yy * 22 + xx) * 40 + cg * 4]) =
        make_int2(pack2(v0, v1), pack2(v2, v3));
  }
  __syncthreads();

  #pragma unroll 1
  for (int s = 0; s < 49; ++s) {
    int ky = s / 7, kx = s - ky * 7;
    short8 bfr[4];
    #pragma unroll
    for (int nt = 0; nt < 4; ++nt) bfr[nt] = wf[((pass * 49 + s) * 4 + nt) * 64 + lane];
    #pragma unroll
    for (int mt = 0; mt < 4; ++mt) {
      int iy = w * 4 + mt + ky;
      int ix = r16 + kx;
      short8 afr = *reinterpret_cast<const short8*>(&s_in[(iy * 22 + ix) * 40 + q * 8]);
      #pragma unroll
      for (int nt = 0; nt < 4; ++nt)
        acc[mt][nt] = __builtin_amdgcn_mfma_f32_16x16x32_bf16(afr, bfr[nt], acc[mt][nt], 0, 0, 0);
    }
  }

  float* dst = part + (size_t)pass * 4718592;
  #pragma unroll
  for (int mt = 0; mt < 4; ++mt) {
    int gy = y0 + w * 4 + mt;
    #pragma unroll
    for (int nt = 0; nt < 4; ++nt) {
      int oc = nt * 16 + r16;
      float4 o;
      o.x = acc[mt][nt][0]; o.y = acc[mt][nt][1];
      o.z = acc[mt][nt][2]; o.w = acc[mt][nt][3];
      *reinterpret_cast<float4*>(&dst[(((size_t)b * 64 + oc) * H + gy) * H + x0 + q * 4]) = o;
    }
  }
}

// ---- reduce 4 partials + bias + BN + GELU -> t0 ---------------------------
__global__ void reduce_up_k(const float* __restrict__ part,
    const float* __restrict__ bias,
    const float* __restrict__ bg, const float* __restrict__ bb,
    const float* __restrict__ bm, const float* __restrict__ bv,
    float* __restrict__ out)
{
  int i4 = blockIdx.x * 256 + threadIdx.x;
  if (i4 >= 1179648) return;
  size_t i = (size_t)i4 * 4;
  const size_t N = 4718592;
  float4 a0 = *reinterpret_cast<const float4*>(part + i);
  float4 a1 = *reinterpret_cast<const float4*>(part + N + i);
  float4 a2 = *reinterpret_cast<const float4*>(part + 2 * N + i);
  float4 a3 = *reinterpret_cast<const float4*>(part + 3 * N + i);
  int oc = (int)((i / 9216) & 63);
  float sc = bg[oc] * rsqrtf(bv[oc] + 1e-5f);
  float sh = bb[oc] - bm[oc] * sc;
  float bi_ = bias[oc];
  float4 o;
  o.x = gelu_f((a0.x + a1.x + a2.x + a3.x + bi_) * sc + sh);
  o.y = gelu_f((a0.y + a1.y + a2.y + a3.y + bi_) * sc + sh);
  o.z = gelu_f((a0.z + a1.z + a2.z + a3.z + bi_) * sc + sh);
  o.w = gelu_f((a0.w + a1.w + a2.w + a3.w + bi_) * sc + sh);
  *reinterpret_cast<float4*>(out + i) = o;
}

// ---- conv_out 7x7 64->1: split-K (16 groups of 4 ch), register-blocked -----
// Block: 128 thr, tile 32w x 64h. Thread: 4 cols x 4 rows.
// part layout: [g][b*36864 + y*192 + x], g in [0,16)
__global__ __launch_bounds__(128) void conv_out_part_k(
    const float* __restrict__ in,   // (8,64,192,192)
    const float* __restrict__ W,    // (1,64,7,7)
    float* __restrict__ part)
{
  const int H = 192;
  int bi = blockIdx.x;
  int g = bi & 15; int tile = bi >> 4;
  int tx = tile % 6; int t2 = tile / 6; int ty = t2 % 3; int b = t2 / 3;
  int x0 = tx * 32, y0 = ty * 64;
  int tid = threadIdx.x;
  int px0 = (tid & 7) * 4;        // col strip
  int r0 = (tid >> 3) * 4;        // row quad (0..60)
  int ch0 = g * 4;

  __shared__ __align__(16) float s_in[4][70][40];

  // stage 4 channels, 70x38 halo
  for (int e = tid; e < 4 * 70 * 38; e += 128) {
    int c = e / 2660; int rr = e % 2660; int yy = rr / 38; int xx = rr % 38;
    int gy = y0 + yy - 3, gx = x0 + xx - 3;
    float v = 0.0f;
    if (gy >= 0 && gy < H && gx >= 0 && gx < H)
      v = in[(((size_t)b * 64 + ch0 + c) * H + gy) * H + gx];
    s_in[c][yy][xx] = v;
  }
  __syncthreads();

  float acc[4][4];
  #pragma unroll
  for (int i = 0; i < 4; ++i)
    #pragma unroll
    for (int p = 0; p < 4; ++p) acc[i][p] = 0.0f;

  #pragma unroll 1
  for (int c = 0; c < 4; ++c) {
    const float* Wc = W + (ch0 + c) * 49;   // uniform -> scalar loads
    #pragma unroll
    for (int iy = 0; iy < 10; ++iy) {
      const float* row = &s_in[c][r0 + iy][px0];
      float4 a0 = *reinterpret_cast<const float4*>(row);
      float4 a1 = *reinterpret_cast<const float4*>(row + 4);
      float4 a2 = *reinterpret_cast<const float4*>(row + 8);
      float rin[12] = {a0.x, a0.y, a0.z, a0.w, a1.x, a1.y, a1.z, a1.w,
                       a2.x, a2.y, a2.z, a2.w};
      int ilo = iy - 6 > 0 ? iy - 6 : 0;
      int ihi = iy < 3 ? iy : 3;
      #pragma unroll
      for (int i = 0; i < 4; ++i) {
        if (i < ilo || i > ihi) continue;
        int ky = iy - i;
        #pragma unroll
        for (int kx = 0; kx < 7; ++kx) {
          float wv = Wc[ky * 7 + kx];
          #pragma unroll
          for (int p = 0; p < 4; ++p)
            acc[i][p] = fmaf(rin[p + kx], wv, acc[i][p]);
        }
      }
    }
  }

  float* dst = part + (size_t)g * 294912 + (size_t)b * 36864;
  #pragma unroll
  for (int i = 0; i < 4; ++i) {
    float4 o = make_float4(acc[i][0], acc[i][1], acc[i][2], acc[i][3]);
    *reinterpret_cast<float4*>(&dst[(y0 + r0 + i) * H + x0 + px0]) = o;
  }
}

// ---- reduce 16 conv_out partials + bias -> out1 ---------------------------
__global__ void reduce_out_k(const float* __restrict__ part,
                             const float* __restrict__ bias,
                             float* __restrict__ out) {
  int i4 = blockIdx.x * 256 + threadIdx.x;
  if (i4 >= 73728) return;
  size_t i = (size_t)i4 * 4;
  float4 s = make_float4(0.f, 0.f, 0.f, 0.f);
  #pragma unroll
  for (int gq = 0; gq < 16; ++gq) {
    float4 a = *reinterpret_cast<const float4*>(part + (size_t)gq * 294912 + i);
    s.x += a.x; s.y += a.y; s.z += a.z; s.w += a.w;
  }
  float bi_ = bias[0];
  float4 o = make_float4(s.x + bi_, s.y + bi_, s.z + bi_, s.w + bi_);
  *reinterpret_cast<float4*>(out + i) = o;
}

// ---- bilinear up2 (96->192), align_corners=True, optional sigmoid ---------
template <bool SIG>
__global__ void up2_k(const float* __restrict__ in, float* __restrict__ out, int total) {
  int i = blockIdx.x * 256 + threadIdx.x;
  if (i >= total) return;
  int x = i % 192; int y = (i / 192) % 192; int bc = i / (192 * 192);
  const float c95 = 95.0f / 191.0f;
  float sy = y * c95; int y0 = (int)sy; int y1 = min(y0 + 1, 95); float wy = sy - (float)y0;
  float sx = x * c95; int x0 = (int)sx; int x1 = min(x0 + 1, 95); float wx = sx - (float)x0;
  const float* p = in + (size_t)bc * 96 * 96;
  float v00 = p[y0 * 96 + x0], v01 = p[y0 * 96 + x1];
  float v10 = p[y1 * 96 + x0], v11 = p[y1 * 96 + x1];
  float v = (1.0f - wx) * ((1.0f - wy) * v00 + wy * v10) +
            wx * ((1.0f - wy) * v01 + wy * v11);
  if (SIG) v = 1.0f / (1.0f + expf(-v));
  out[i] = v;
}

// ---- diff map, vectorized: 2 outputs/thread, float4 loads ------------------
__global__ void pools_k(const float* __restrict__ small, const float* __restrict__ x,
                        float* __restrict__ out) {
  int i = blockIdx.x * 256 + threadIdx.x;
  if (i >= 8 * 96 * 48) return;
  int xp = i % 48; int y = (i / 48) % 96; int b = i / (48 * 96);
  float s1a = 0.f, s2a = 0.f, s1b = 0.f, s2b = 0.f;
  for (int c = 0; c < 64; ++c) {
    size_t base = (((size_t)b * 64 + c) * 192 + 2 * y) * 192 + 4 * xp;
    float4 sr0 = *reinterpret_cast<const float4*>(small + base);
    float4 sr1 = *reinterpret_cast<const float4*>(small + base + 192);
    float4 xr0 = *reinterpret_cast<const float4*>(x + base);
    float4 xr1 = *reinterpret_cast<const float4*>(x + base + 192);
    float avgSa = 0.25f * (sr0.x + sr0.y + sr1.x + sr1.y);
    float maxSa = fmaxf(fmaxf(sr0.x, sr0.y), fmaxf(sr1.x, sr1.y));
    float avgXa = 0.25f * (xr0.x + xr0.y + xr1.x + xr1.y);
    float maxXa = fmaxf(fmaxf(xr0.x, xr0.y), fmaxf(xr1.x, xr1.y));
    float d1a = avgSa - maxXa; s1a = fmaf(d1a, d1a, s1a);
    float d2a = avgXa - maxSa; s2a = fmaf(d2a, d2a, s2a);
    float avgSb = 0.25f * (sr0.z + sr0.w + sr1.z + sr1.w);
    float maxSb = fmaxf(fmaxf(sr0.z, sr0.w), fmaxf(sr1.z, sr1.w));
    float avgXb = 0.25f * (xr0.z + xr0.w + xr1.z + xr1.w);
    float maxXb = fmaxf(fmaxf(xr0.z, xr0.w), fmaxf(xr1.z, xr1.w));
    float d1b = avgSb - maxXb; s1b = fmaf(d1b, d1b, s1b);
    float d2b = avgXb - maxSb; s2b = fmaf(d2b, d2b, s2b);
  }
  size_t o = ((size_t)b * 96 + y) * 96 + 2 * xp;
  out[o] = sqrtf(s1a) + sqrtf(s2a);
  out[o + 1] = sqrtf(s1b) + sqrtf(s2b);
}

// ---- scale map: (dilate3(iM)-iM) + (dilate3(dM)-dM) + 1 -------------------
__global__ void scale_k(const float* __restrict__ iM, const float* __restrict__ dM,
                        float* __restrict__ out) {
  int i = blockIdx.x * 256 + threadIdx.x;
  if (i >= 8 * 192 * 192) return;
  int x = i % 192; int y = (i / 192) % 192; int b = i / (192 * 192);
  const float* pi = iM + (size_t)b * 192 * 192;
  const float* pd = dM + (size_t)b * 192 * 192;
  float mi = -1e30f, md = -1e30f;
  for (int dy = -1; dy <= 1; ++dy) {
    int yy = y + dy;
    if (yy < 0 || yy >= 192) continue;
    for (int dx = -1; dx <= 1; ++dx) {
      int xx = x + dx;
      if (xx < 0 || xx >= 192) continue;
      mi = fmaxf(mi, pi[yy * 192 + xx]);
      md = fmaxf(md, pd[yy * 192 + xx]);
    }
  }
  out[i] = (mi - pi[y * 192 + x]) + (md - pd[y * 192 + x]) + 1.0f;
}

// ---------------------------------------------------------------------------
extern "C" void kernel_launch(void* const* d_in, const int* in_sizes, int n_in,
                              void* d_out, int out_size, void* d_ws, size_t ws_size,
                              hipStream_t stream) {
  (void)in_sizes; (void)n_in; (void)out_size; (void)ws_size;
  const float* x       = (const float*)d_in[0];
  const float* small_x = (const float*)d_in[1];
  const float* in_map  = (const float*)d_in[2];
  const float* W_up = (const float*)d_in[3];  const float* b_up = (const float*)d_in[4];
  const float* g_up = (const float*)d_in[5];  const float* be_up = (const float*)d_in[6];
  const float* m_up = (const float*)d_in[7];  const float* v_up = (const float*)d_in[8];
  const float* W_c2 = (const float*)d_in[9];  const float* b_c2 = (const float*)d_in[10];
  const float* W_d1 = (const float*)d_in[11]; const float* b_d1 = (const float*)d_in[12];
  const float* g_d1 = (const float*)d_in[13]; const float* be_d1 = (const float*)d_in[14];
  const float* m_d1 = (const float*)d_in[15]; const float* v_d1 = (const float*)d_in[16];
  const float* W_d2 = (const float*)d_in[17]; const float* b_d2 = (const float*)d_in[18];
  const float* g_d2 = (const float*)d_in[19]; const float* be_d2 = (const float*)d_in[20];
  const float* m_d2 = (const float*)d_in[21]; const float* v_d2 = (const float*)d_in[22];
  const float* W_d3 = (const float*)d_in[23]; const float* b_d3 = (const float*)d_in[24];
  const float* g_d3 = (const float*)d_in[25]; const float* be_d3 = (const float*)d_in[26];
  const float* m_d3 = (const float*)d_in[27]; const float* v_d3 = (const float*)d_in[28];
  const float* W_out = (const float*)d_in[29]; const float* b_out = (const float*)d_in[30];
  const float* beta = (const float*)d_in[31];

  const size_t SZ = 18874368;  // 8*64*192*192
  float* ws = (float*)d_ws;
  float* small = ws;            // SZ
  float* fn    = ws + SZ;       // SZ ; also split-K partial buffer for conv_up
  float* part  = fn;
  float* r1    = ws + 2 * SZ;   // SZ ; t0 aliases front; conv_out partials after d2
  float* t0    = r1;            // 4718592 floats
  float* r2    = fn;            // fn dead after conv_d1
  float* partO = r1;            // r1 dead after conv_d2; 16*294912 = 4718592 floats
  float* ext   = ws + 3 * SZ;
  float* diff96 = ext;                 // 73728
  float* iMap   = diff96 + 73728;      // 294912
  float* dMap   = iMap + 294912;       // 294912
  float* scaleM = dMap + 294912;       // 294912
  short* wf_up = (short*)(scaleM + 294912);  // 401408 shorts
  short* wf_c2 = wf_up + 401408;             // 36864
  short* wf_d1 = wf_c2 + 36864;              // 73728
  short* wf_d2 = wf_d1 + 73728;              // 36864
  short* wf_d3 = wf_d2 + 36864;              // 36864

  float* out0 = (float*)d_out;         // r   (8,64,192,192)
  float* out1 = out0 + SZ;             // map (8,1,192,192)

  // B-fragment precompute
  frag_up_k<<<1568, 256, 0, stream>>>(W_up, wf_up);
  frag3_k<<<144, 256, 0, stream>>>(W_c2, wf_c2, 64, 0);
  frag3_k<<<144, 256, 0, stream>>>(W_d1, wf_d1, 128, 0);
  frag3_k<<<144, 256, 0, stream>>>(W_d1, wf_d1 + 36864, 128, 64);
  frag3_k<<<144, 256, 0, stream>>>(W_d2, wf_d2, 64, 0);
  frag3_k<<<144, 256, 0, stream>>>(W_d3, wf_d3, 64, 0);

  // up path
  conv_up_m_k<<<1152, 256, 0, stream>>>(small_x, wf_up, part);
  reduce_up_k<<<4608, 256, 0, stream>>>(part, b_up, g_up, be_up, m_up, v_up, t0);
  up2_k<false><<<(int)(SZ / 256), 256, 0, stream>>>(t0, small, (int)SZ);

  // uncertainty maps
  pools_k<<<144, 256, 0, stream>>>(small, x, diff96);
  up2_k<true><<<1152, 256, 0, stream>>>(in_map, iMap, 8 * 192 * 192);
  up2_k<true><<<1152, 256, 0, stream>>>(diff96, dMap, 8 * 192 * 192);
  scale_k<<<1152, 256, 0, stream>>>(iMap, dMap, scaleM);

  // conv chain (MFMA)
  conv3m_k<false, true, false, true><<<1152, 256, 0, stream>>>(
      x, nullptr, wf_c2, b_c2, scaleM, nullptr, nullptr, nullptr, nullptr, beta, fn);
  conv3m_k<true, false, true, false><<<1152, 256, 0, stream>>>(
      small, fn, wf_d1, b_d1, nullptr, g_d1, be_d1, m_d1, v_d1, nullptr, r1);
  conv3m_k<false, false, true, false><<<1152, 256, 0, stream>>>(
      r1, nullptr, wf_d2, b_d2, nullptr, g_d2, be_d2, m_d2, v_d2, nullptr, r2);
  conv3m_k<false, false, true, false><<<1152, 256, 0, stream>>>(
      r2, nullptr, wf_d3, b_d3, nullptr, g_d3, be_d3, m_d3, v_d3, nullptr, out0);

  // output head: split-K register-blocked conv 7x7 64->1
  conv_out_part_k<<<2304, 128, 0, stream>>>(out0, W_out, partO);
  reduce_out_k<<<288, 256, 0, stream>>>(partO, b_out, out1);
}

// Round 4
// 866.838 us; speedup vs baseline: 3.6716x; 1.0786x over previous
//
#include <hip/hip_runtime.h>
#include <math.h>

// ---------------------------------------------------------------------------
// FGC_23957327577330 — round 4: bf16 NHWC activations end-to-end.
//   All conv-chain tensors stored NHWC bf16: staging = contiguous 16B loads.
//   MFMA operands swapped (A=weights m=oc, B=pixels n=x) -> packed bf16 stores.
//   K-loop: explicit next-step weight prefetch, full unroll.
//   Epilogue: per-oc A,B fold of bias/BN/beta; tanh-GELU (|err|<=3e-4).
// ---------------------------------------------------------------------------

#define DI __device__ __forceinline__

typedef __attribute__((ext_vector_type(8))) short short8;
typedef __attribute__((ext_vector_type(4))) float floatx4;

DI float gelu_f(float x) {
  // tanh-form GELU via sigmoid: x * sigmoid(1.5957691*x + 0.07135481*x^3)
  float u = x * (1.5957691216f + 0.0713548162f * x * x);
  return x / (1.0f + __expf(-u));
}

DI unsigned short f2b(float f) {          // fp32 -> bf16, round-to-nearest-even
  unsigned u = __float_as_uint(f);
  u += 0x7FFFu + ((u >> 16) & 1u);
  return (unsigned short)(u >> 16);
}
DI unsigned pack2(float a, float b) {
  return (unsigned)f2b(a) | ((unsigned)f2b(b) << 16);
}
DI float b2f(short s) { return __uint_as_float(((unsigned)(unsigned short)s) << 16); }

// ---- epilogue fold: v = f(acc*A + B) ---------------------------------------
__global__ void epi_prep_k(const float* __restrict__ bias,
                           const float* __restrict__ g, const float* __restrict__ be,
                           const float* __restrict__ m, const float* __restrict__ v,
                           const float* __restrict__ betap, int useBN,
                           float* __restrict__ A, float* __restrict__ B) {
  int oc = threadIdx.x;
  if (oc >= 64) return;
  if (useBN) {
    float giv = g[oc] * rsqrtf(v[oc] + 1e-5f);
    A[oc] = giv;
    B[oc] = (bias[oc] - m[oc]) * giv + be[oc];
  } else {
    float bt = betap[0];
    A[oc] = bt;
    B[oc] = bias[oc] * bt;
  }
}

// ---- weight fragments, 3x3: 18 ksteps, lane holds oc=(nt*16+lane&15), ic=(q*8+j)
__global__ void frag3_k(const float* __restrict__ W, short* __restrict__ wf,
                        int CIN, int icg0) {
  int i = blockIdx.x * 256 + threadIdx.x;
  if (i >= 18 * 4 * 64 * 8) return;
  int j = i & 7; int lane = (i >> 3) & 63; int nt = (i >> 9) & 3; int s = i >> 11;
  int q = lane >> 4, r16 = lane & 15;
  int tap = s >> 1, ich = s & 1;
  int ky = tap / 3, kx = tap % 3;
  int ic = icg0 + ich * 32 + q * 8 + j;
  int oc = nt * 16 + r16;
  wf[i] = (short)f2b(W[((oc * CIN + ic) * 3 + ky) * 3 + kx]);
}

// ---- weight fragments, conv_up 7x7 128->64: 196 ksteps ---------------------
__global__ void frag_up_k(const float* __restrict__ W, short* __restrict__ wf) {
  int i = blockIdx.x * 256 + threadIdx.x;
  if (i >= 196 * 4 * 64 * 8) return;
  int j = i & 7; int lane = (i >> 3) & 63; int nt = (i >> 9) & 3; int s = i >> 11;
  int q = lane >> 4, r16 = lane & 15;
  int pass = s / 49, tap = s % 49;
  int ky = tap / 7, kx = tap % 7;
  int ic = pass * 32 + q * 8 + j;
  int oc = nt * 16 + r16;
  wf[i] = (short)f2b(W[((oc * 128 + ic) * 7 + ky) * 7 + kx]);
}

// ---- NCHW fp32 -> NHWC bf16 ------------------------------------------------
__global__ void to_nhwc_k(const float* __restrict__ in, short* __restrict__ out,
                          int C8, int HW, int total) {
  int i = blockIdx.x * 256 + threadIdx.x;
  if (i >= total) return;
  int cu = i % C8; int p = i / C8;
  int b = p / HW; int pix = p % HW;
  const float* src = in + ((size_t)b * C8 * 8 + cu * 8) * HW + pix;
  int4 o;
  unsigned* op = (unsigned*)&o;
  #pragma unroll
  for (int j = 0; j < 4; ++j)
    op[j] = pack2(src[(2 * j) * (size_t)HW], src[(2 * j + 1) * (size_t)HW]);
  *reinterpret_cast<int4*>(out + (size_t)p * C8 * 8 + cu * 8) = o;
}

// ---- MFMA 3x3 conv @192, NHWC bf16 in/out ---------------------------------
template <bool TWO_IN, bool SCALE_IN, bool GELU_OUT, bool OUT_NCHW>
__global__ __launch_bounds__(256, 3) void conv3h_k(
    const short* __restrict__ inA, const short* __restrict__ inB,
    const short* __restrict__ wfrag,
    const float* __restrict__ Aepi, const float* __restrict__ Bepi,
    const float* __restrict__ scale,
    short* __restrict__ outH, float* __restrict__ outF)
{
  const int H = 192;
  int bi = blockIdx.x;
  int tx = bi % 12, t2 = bi / 12, ty = t2 % 12, b = t2 / 12;
  int x0 = tx * 16, y0 = ty * 16;
  int tid = threadIdx.x;
  int w = tid >> 6, lane = tid & 63, q = lane >> 4, r16 = lane & 15;

  __shared__ __align__(16) short s_in[324 * 72];  // [pixel][ic], pad 64->72
  const short8* wf = (const short8*)wfrag;

  floatx4 acc[4][4];
  #pragma unroll
  for (int a = 0; a < 4; ++a)
    #pragma unroll
    for (int c = 0; c < 4; ++c) acc[a][c] = (floatx4){0.f, 0.f, 0.f, 0.f};

  for (int half = 0; half < (TWO_IN ? 2 : 1); ++half) {
    const short* src = half ? inB : inA;
    if (half) __syncthreads();
    for (int u = tid; u < 2592; u += 256) {
      int px = u >> 3, cu = u & 7;
      int yy = px / 18, xx = px - yy * 18;
      int gy = y0 + yy - 1, gx = x0 + xx - 1;
      int4 v = make_int4(0, 0, 0, 0);
      if (gy >= 0 && gy < H && gx >= 0 && gx < H) {
        v = *reinterpret_cast<const int4*>(src + (((size_t)b * H + gy) * H + gx) * 64 + cu * 8);
        if (SCALE_IN) {
          float sc = scale[((size_t)b * H + gy) * H + gx];
          short* sp = (short*)&v;
          #pragma unroll
          for (int j = 0; j < 8; ++j) sp[j] = (short)f2b(b2f(sp[j]) * sc);
        }
      }
      *reinterpret_cast<int4*>(&s_in[px * 72 + cu * 8]) = v;
    }
    __syncthreads();

    const short8* wfh = wf + half * (18 * 4 * 64);
    short8 wcur[4];
    #pragma unroll
    for (int ot = 0; ot < 4; ++ot) wcur[ot] = wfh[ot * 64 + lane];
    #pragma unroll
    for (int s = 0; s < 18; ++s) {
      short8 wnxt[4];
      if (s < 17) {
        #pragma unroll
        for (int ot = 0; ot < 4; ++ot) wnxt[ot] = wfh[((s + 1) * 4 + ot) * 64 + lane];
      }
      int tap = s >> 1, ich = s & 1;
      int ky = tap / 3, kx = tap - ky * 3;
      #pragma unroll
      for (int yt = 0; yt < 4; ++yt) {
        int iy = w * 4 + yt + ky;
        int ix = r16 + kx;
        short8 pfr = *reinterpret_cast<const short8*>(
            &s_in[(iy * 18 + ix) * 72 + ich * 32 + q * 8]);
        #pragma unroll
        for (int ot = 0; ot < 4; ++ot)
          acc[yt][ot] = __builtin_amdgcn_mfma_f32_16x16x32_bf16(wcur[ot], pfr, acc[yt][ot], 0, 0, 0);
      }
      #pragma unroll
      for (int ot = 0; ot < 4; ++ot) wcur[ot] = wnxt[ot];
    }
  }

  // D: row = oc (q*4+rg within ot*16), col = pixel x (r16)
  #pragma unroll
  for (int ot = 0; ot < 4; ++ot) {
    float4 A4 = *reinterpret_cast<const float4*>(Aepi + ot * 16 + q * 4);
    float4 B4 = *reinterpret_cast<const float4*>(Bepi + ot * 16 + q * 4);
    #pragma unroll
    for (int yt = 0; yt < 4; ++yt) {
      int gy = y0 + w * 4 + yt;
      float v0 = acc[yt][ot][0] * A4.x + B4.x;
      float v1 = acc[yt][ot][1] * A4.y + B4.y;
      float v2 = acc[yt][ot][2] * A4.z + B4.z;
      float v3 = acc[yt][ot][3] * A4.w + B4.w;
      if (GELU_OUT) { v0 = gelu_f(v0); v1 = gelu_f(v1); v2 = gelu_f(v2); v3 = gelu_f(v3); }
      if (OUT_NCHW) {
        int oc = ot * 16 + q * 4;
        size_t base = (((size_t)b * 64 + oc) * H + gy) * H + x0 + r16;
        outF[base] = v0;
        outF[base + (size_t)H * H] = v1;
        outF[base + 2 * (size_t)H * H] = v2;
        outF[base + 3 * (size_t)H * H] = v3;
      } else {
        uint2 pk;
        pk.x = pack2(v0, v1);
        pk.y = pack2(v2, v3);
        *reinterpret_cast<uint2*>(
            &outH[(((size_t)b * H + gy) * H + x0 + r16) * 64 + ot * 16 + q * 4]) = pk;
      }
    }
  }
}

// ---- MFMA conv_up 7x7 128->64 @96, NHWC bf16 in, NHWC fp32 partials --------
__global__ __launch_bounds__(256, 3) void conv_up_h_k(
    const short* __restrict__ in,   // sxh (8,96,96,128)
    const short* __restrict__ wfrag,
    float* __restrict__ part)
{
  const int H = 96;
  int bi = blockIdx.x;
  int pass = bi & 3; int tile = bi >> 2;
  int tx = tile % 6, t2 = tile / 6, ty = t2 % 6, b = t2 / 6;
  int x0 = tx * 16, y0 = ty * 16;
  int tid = threadIdx.x;
  int w = tid >> 6, lane = tid & 63, q = lane >> 4, r16 = lane & 15;

  __shared__ __align__(16) short s_in[484 * 40];  // [pixel][32ic], pad 32->40
  const short8* wf = (const short8*)wfrag;

  floatx4 acc[4][4];
  #pragma unroll
  for (int a = 0; a < 4; ++a)
    #pragma unroll
    for (int c = 0; c < 4; ++c) acc[a][c] = (floatx4){0.f, 0.f, 0.f, 0.f};

  for (int u = tid; u < 1936; u += 256) {
    int px = u >> 2, cu = u & 3;
    int yy = px / 22, xx = px - yy * 22;
    int gy = y0 + yy - 3, gx = x0 + xx - 3;
    int4 v = make_int4(0, 0, 0, 0);
    if (gy >= 0 && gy < H && gx >= 0 && gx < H)
      v = *reinterpret_cast<const int4*>(
          in + (((size_t)b * H + gy) * H + gx) * 128 + pass * 32 + cu * 8);
    *reinterpret_cast<int4*>(&s_in[px * 40 + cu * 8]) = v;
  }
  __syncthreads();

  const short8* wfp = wf + pass * (49 * 4 * 64);
  short8 wcur[4];
  #pragma unroll
  for (int ot = 0; ot < 4; ++ot) wcur[ot] = wfp[ot * 64 + lane];
  for (int s = 0; s < 49; ++s) {
    short8 wnxt[4];
    if (s < 48) {
      #pragma unroll
      for (int ot = 0; ot < 4; ++ot) wnxt[ot] = wfp[((s + 1) * 4 + ot) * 64 + lane];
    }
    int ky = s / 7, kx = s - ky * 7;
    #pragma unroll
    for (int yt = 0; yt < 4; ++yt) {
      int iy = w * 4 + yt + ky;
      int ix = r16 + kx;
      short8 pfr = *reinterpret_cast<const short8*>(&s_in[(iy * 22 + ix) * 40 + q * 8]);
      #pragma unroll
      for (int ot = 0; ot < 4; ++ot)
        acc[yt][ot] = __builtin_amdgcn_mfma_f32_16x16x32_bf16(wcur[ot], pfr, acc[yt][ot], 0, 0, 0);
    }
    #pragma unroll
    for (int ot = 0; ot < 4; ++ot) wcur[ot] = wnxt[ot];
  }

  float* dst = part + (size_t)pass * 4718592;
  #pragma unroll
  for (int yt = 0; yt < 4; ++yt) {
    int gy = y0 + w * 4 + yt;
    #pragma unroll
    for (int ot = 0; ot < 4; ++ot) {
      float4 o;
      o.x = acc[yt][ot][0]; o.y = acc[yt][ot][1];
      o.z = acc[yt][ot][2]; o.w = acc[yt][ot][3];
      *reinterpret_cast<float4*>(
          &dst[(((size_t)b * H + gy) * H + x0 + r16) * 64 + ot * 16 + q * 4]) = o;
    }
  }
}

// ---- reduce 4 conv_up partials (NHWC fp32) + A,B + GELU -> t0h bf16 --------
__global__ void reduce_up_k(const float* __restrict__ part,
                            const float* __restrict__ A, const float* __restrict__ B,
                            short* __restrict__ out)
{
  int i8 = blockIdx.x * 256 + threadIdx.x;
  if (i8 >= 589824) return;
  size_t base = (size_t)i8 * 8;
  const size_t N = 4718592;
  float s[8];
  #pragma unroll
  for (int j = 0; j < 8; ++j) s[j] = 0.f;
  #pragma unroll
  for (int p = 0; p < 4; ++p) {
    float4 a = *reinterpret_cast<const float4*>(part + p * N + base);
    float4 bq = *reinterpret_cast<const float4*>(part + p * N + base + 4);
    s[0] += a.x; s[1] += a.y; s[2] += a.z; s[3] += a.w;
    s[4] += bq.x; s[5] += bq.y; s[6] += bq.z; s[7] += bq.w;
  }
  int oc0 = (int)(base & 63);
  int4 o;
  unsigned* op = (unsigned*)&o;
  #pragma unroll
  for (int j = 0; j < 4; ++j) {
    float va = gelu_f(s[2 * j] * A[oc0 + 2 * j] + B[oc0 + 2 * j]);
    float vb = gelu_f(s[2 * j + 1] * A[oc0 + 2 * j + 1] + B[oc0 + 2 * j + 1]);
    op[j] = pack2(va, vb);
  }
  *reinterpret_cast<int4*>(out + base) = o;
}

// ---- bilinear up2 96->192, NHWC bf16, align_corners=True -------------------
__global__ void up2h_k(const short* __restrict__ in, short* __restrict__ out) {
  int i = blockIdx.x * 256 + threadIdx.x;
  if (i >= 2359296) return;
  int cu = i & 7; int p = i >> 3;
  int x = p % 192; int t = p / 192; int y = t % 192; int b = t / 192;
  const float c95 = 95.0f / 191.0f;
  float sy = y * c95; int y0i = (int)sy; int y1i = min(y0i + 1, 95); float wy = sy - (float)y0i;
  float sx = x * c95; int x0i = (int)sx; int x1i = min(x0i + 1, 95); float wx = sx - (float)x0i;
  const short* base = in + (size_t)b * 96 * 96 * 64;
  int4 a00 = *reinterpret_cast<const int4*>(base + (y0i * 96 + x0i) * 64 + cu * 8);
  int4 a01 = *reinterpret_cast<const int4*>(base + (y0i * 96 + x1i) * 64 + cu * 8);
  int4 a10 = *reinterpret_cast<const int4*>(base + (y1i * 96 + x0i) * 64 + cu * 8);
  int4 a11 = *reinterpret_cast<const int4*>(base + (y1i * 96 + x1i) * 64 + cu * 8);
  const short* s00 = (const short*)&a00; const short* s01 = (const short*)&a01;
  const short* s10 = (const short*)&a10; const short* s11 = (const short*)&a11;
  float w00 = (1.f - wy) * (1.f - wx), w01 = (1.f - wy) * wx;
  float w10 = wy * (1.f - wx), w11 = wy * wx;
  int4 o;
  unsigned* op = (unsigned*)&o;
  #pragma unroll
  for (int j = 0; j < 4; ++j) {
    float va = b2f(s00[2 * j]) * w00 + b2f(s01[2 * j]) * w01 +
               b2f(s10[2 * j]) * w10 + b2f(s11[2 * j]) * w11;
    float vb = b2f(s00[2 * j + 1]) * w00 + b2f(s01[2 * j + 1]) * w01 +
               b2f(s10[2 * j + 1]) * w10 + b2f(s11[2 * j + 1]) * w11;
    op[j] = pack2(va, vb);
  }
  *reinterpret_cast<int4*>(out + (size_t)p * 64 + cu * 8) = o;
}

// ---- diff map from NHWC bf16 tensors --------------------------------------
__global__ void pools_h_k(const short* __restrict__ small, const short* __restrict__ xh,
                          float* __restrict__ out) {
  int i = blockIdx.x * 256 + threadIdx.x;
  if (i >= 73728) return;
  int x96 = i % 96; int y96 = (i / 96) % 96; int b = i / 9216;
  size_t base = (((size_t)b * 192 + 2 * y96) * 192 + 2 * x96) * 64;
  const int RS = 192 * 64;
  float s1 = 0.f, s2 = 0.f;
  for (int cu = 0; cu < 8; ++cu) {
    int4 sa0 = *reinterpret_cast<const int4*>(small + base + cu * 8);
    int4 sa1 = *reinterpret_cast<const int4*>(small + base + 64 + cu * 8);
    int4 sa2 = *reinterpret_cast<const int4*>(small + base + RS + cu * 8);
    int4 sa3 = *reinterpret_cast<const int4*>(small + base + RS + 64 + cu * 8);
    int4 xa0 = *reinterpret_cast<const int4*>(xh + base + cu * 8);
    int4 xa1 = *reinterpret_cast<const int4*>(xh + base + 64 + cu * 8);
    int4 xa2 = *reinterpret_cast<const int4*>(xh + base + RS + cu * 8);
    int4 xa3 = *reinterpret_cast<const int4*>(xh + base + RS + 64 + cu * 8);
    const short* p0 = (const short*)&sa0; const short* p1 = (const short*)&sa1;
    const short* p2 = (const short*)&sa2; const short* p3 = (const short*)&sa3;
    const short* q0 = (const short*)&xa0; const short* q1 = (const short*)&xa1;
    const short* q2 = (const short*)&xa2; const short* q3 = (const short*)&xa3;
    #pragma unroll
    for (int j = 0; j < 8; ++j) {
      float a0 = b2f(p0[j]), a1 = b2f(p1[j]), a2 = b2f(p2[j]), a3 = b2f(p3[j]);
      float b0 = b2f(q0[j]), b1 = b2f(q1[j]), b2 = b2f(q2[j]), b3 = b2f(q3[j]);
      float avgS = 0.25f * (a0 + a1 + a2 + a3);
      float maxS = fmaxf(fmaxf(a0, a1), fmaxf(a2, a3));
      float avgX = 0.25f * (b0 + b1 + b2 + b3);
      float maxX = fmaxf(fmaxf(b0, b1), fmaxf(b2, b3));
      float d1 = avgS - maxX; s1 = fmaf(d1, d1, s1);
      float d2 = avgX - maxS; s2 = fmaf(d2, d2, s2);
    }
  }
  out[((size_t)b * 96 + y96) * 96 + x96] = sqrtf(s1) + sqrtf(s2);
}

// ---- bilinear up2 (96->192) fp32, optional sigmoid (maps) ------------------
template <bool SIG>
__global__ void up2_k(const float* __restrict__ in, float* __restrict__ out, int total) {
  int i = blockIdx.x * 256 + threadIdx.x;
  if (i >= total) return;
  int x = i % 192; int y = (i / 192) % 192; int bc = i / (192 * 192);
  const float c95 = 95.0f / 191.0f;
  float sy = y * c95; int y0 = (int)sy; int y1 = min(y0 + 1, 95); float wy = sy - (float)y0;
  float sx = x * c95; int x0 = (int)sx; int x1 = min(x0 + 1, 95); float wx = sx - (float)x0;
  const float* p = in + (size_t)bc * 96 * 96;
  float v00 = p[y0 * 96 + x0], v01 = p[y0 * 96 + x1];
  float v10 = p[y1 * 96 + x0], v11 = p[y1 * 96 + x1];
  float v = (1.0f - wx) * ((1.0f - wy) * v00 + wy * v10) +
            wx * ((1.0f - wy) * v01 + wy * v11);
  if (SIG) v = 1.0f / (1.0f + expf(-v));
  out[i] = v;
}

// ---- scale map: (dilate3(iM)-iM) + (dilate3(dM)-dM) + 1 -------------------
__global__ void scale_k(const float* __restrict__ iM, const float* __restrict__ dM,
                        float* __restrict__ out) {
  int i = blockIdx.x * 256 + threadIdx.x;
  if (i >= 8 * 192 * 192) return;
  int x = i % 192; int y = (i / 192) % 192; int b = i / (192 * 192);
  const float* pi = iM + (size_t)b * 192 * 192;
  const float* pd = dM + (size_t)b * 192 * 192;
  float mi = -1e30f, md = -1e30f;
  for (int dy = -1; dy <= 1; ++dy) {
    int yy = y + dy;
    if (yy < 0 || yy >= 192) continue;
    for (int dx = -1; dx <= 1; ++dx) {
      int xx = x + dx;
      if (xx < 0 || xx >= 192) continue;
      mi = fmaxf(mi, pi[yy * 192 + xx]);
      md = fmaxf(md, pd[yy * 192 + xx]);
    }
  }
  out[i] = (mi - pi[y * 192 + x]) + (md - pd[y * 192 + x]) + 1.0f;
}

// ---- conv_out 7x7 64->1: split-K reg-blocked (reads fp32 NCHW out0) --------
__global__ __launch_bounds__(128) void conv_out_part_k(
    const float* __restrict__ in, const float* __restrict__ W,
    float* __restrict__ part)
{
  const int H = 192;
  int bi = blockIdx.x;
  int g = bi & 15; int tile = bi >> 4;
  int tx = tile % 6; int t2 = tile / 6; int ty = t2 % 3; int b = t2 / 3;
  int x0 = tx * 32, y0 = ty * 64;
  int tid = threadIdx.x;
  int px0 = (tid & 7) * 4;
  int r0 = (tid >> 3) * 4;
  int ch0 = g * 4;

  __shared__ __align__(16) float s_in[4][70][40];

  for (int e = tid; e < 4 * 70 * 38; e += 128) {
    int c = e / 2660; int rr = e % 2660; int yy = rr / 38; int xx = rr % 38;
    int gy = y0 + yy - 3, gx = x0 + xx - 3;
    float v = 0.0f;
    if (gy >= 0 && gy < H && gx >= 0 && gx < H)
      v = in[(((size_t)b * 64 + ch0 + c) * H + gy) * H + gx];
    s_in[c][yy][xx] = v;
  }
  __syncthreads();

  float acc[4][4];
  #pragma unroll
  for (int i = 0; i < 4; ++i)
    #pragma unroll
    for (int p = 0; p < 4; ++p) acc[i][p] = 0.0f;

  #pragma unroll 1
  for (int c = 0; c < 4; ++c) {
    const float* Wc = W + (ch0 + c) * 49;
    #pragma unroll
    for (int iy = 0; iy < 10; ++iy) {
      const float* row = &s_in[c][r0 + iy][px0];
      float4 a0 = *reinterpret_cast<const float4*>(row);
      float4 a1 = *reinterpret_cast<const float4*>(row + 4);
      float4 a2 = *reinterpret_cast<const float4*>(row + 8);
      float rin[12] = {a0.x, a0.y, a0.z, a0.w, a1.x, a1.y, a1.z, a1.w,
                       a2.x, a2.y, a2.z, a2.w};
      int ilo = iy - 6 > 0 ? iy - 6 : 0;
      int ihi = iy < 3 ? iy : 3;
      #pragma unroll
      for (int i = 0; i < 4; ++i) {
        if (i < ilo || i > ihi) continue;
        int ky = iy - i;
        #pragma unroll
        for (int kx = 0; kx < 7; ++kx) {
          float wv = Wc[ky * 7 + kx];
          #pragma unroll
          for (int p = 0; p < 4; ++p)
            acc[i][p] = fmaf(rin[p + kx], wv, acc[i][p]);
        }
      }
    }
  }

  float* dst = part + (size_t)g * 294912 + (size_t)b * 36864;
  #pragma unroll
  for (int i = 0; i < 4; ++i) {
    float4 o = make_float4(acc[i][0], acc[i][1], acc[i][2], acc[i][3]);
    *reinterpret_cast<float4*>(&dst[(y0 + r0 + i) * H + x0 + px0]) = o;
  }
}

__global__ void reduce_out_k(const float* __restrict__ part,
                             const float* __restrict__ bias,
                             float* __restrict__ out) {
  int i4 = blockIdx.x * 256 + threadIdx.x;
  if (i4 >= 73728) return;
  size_t i = (size_t)i4 * 4;
  float4 s = make_float4(0.f, 0.f, 0.f, 0.f);
  #pragma unroll
  for (int gq = 0; gq < 16; ++gq) {
    float4 a = *reinterpret_cast<const float4*>(part + (size_t)gq * 294912 + i);
    s.x += a.x; s.y += a.y; s.z += a.z; s.w += a.w;
  }
  float bi_ = bias[0];
  float4 o = make_float4(s.x + bi_, s.y + bi_, s.z + bi_, s.w + bi_);
  *reinterpret_cast<float4*>(out + i) = o;
}

// ---------------------------------------------------------------------------
extern "C" void kernel_launch(void* const* d_in, const int* in_sizes, int n_in,
                              void* d_out, int out_size, void* d_ws, size_t ws_size,
                              hipStream_t stream) {
  (void)in_sizes; (void)n_in; (void)out_size; (void)ws_size;
  const float* x       = (const float*)d_in[0];
  const float* small_x = (const float*)d_in[1];
  const float* in_map  = (const float*)d_in[2];
  const float* W_up = (const float*)d_in[3];  const float* b_up = (const float*)d_in[4];
  const float* g_up = (const float*)d_in[5];  const float* be_up = (const float*)d_in[6];
  const float* m_up = (const float*)d_in[7];  const float* v_up = (const float*)d_in[8];
  const float* W_c2 = (const float*)d_in[9];  const float* b_c2 = (const float*)d_in[10];
  const float* W_d1 = (const float*)d_in[11]; const float* b_d1 = (const float*)d_in[12];
  const float* g_d1 = (const float*)d_in[13]; const float* be_d1 = (const float*)d_in[14];
  const float* m_d1 = (const float*)d_in[15]; const float* v_d1 = (const float*)d_in[16];
  const float* W_d2 = (const float*)d_in[17]; const float* b_d2 = (const float*)d_in[18];
  const float* g_d2 = (const float*)d_in[19]; const float* be_d2 = (const float*)d_in[20];
  const float* m_d2 = (const float*)d_in[21]; const float* v_d2 = (const float*)d_in[22];
  const float* W_d3 = (const float*)d_in[23]; const float* b_d3 = (const float*)d_in[24];
  const float* g_d3 = (const float*)d_in[25]; const float* be_d3 = (const float*)d_in[26];
  const float* m_d3 = (const float*)d_in[27]; const float* v_d3 = (const float*)d_in[28];
  const float* W_out = (const float*)d_in[29]; const float* b_out = (const float*)d_in[30];
  const float* beta = (const float*)d_in[31];

  const size_t SZ = 18874368;  // 8*64*192*192
  float* ws = (float*)d_ws;
  // partU (4 x 4,718,592 fp32) dead after reduce_up -> reused as fnh + r2h
  float* partU = ws;                              // 18,874,368 floats
  short* fnh   = (short*)partU;                   // 18,874,368 shorts
  short* r2h   = fnh + 18874368;                  // 18,874,368 shorts
  float* p1 = ws + 18874368;
  short* xh  = (short*)p1;                        // 18,874,368 shorts
  float* p2 = p1 + 9437184;
  short* sxh = (short*)p2;                        // 9,437,184 shorts
  float* p3 = p2 + 4718592;
  short* t0h = (short*)p3;                        // 4,718,592 shorts
  float* p4 = p3 + 2359296;
  short* smallh = (short*)p4;                     // 18,874,368 shorts
  float* p5 = p4 + 9437184;
  short* r1h = (short*)p5;                        // 18,874,368 shorts
  float* partO = p5;                              // alias; r1h dead after conv_d2
  float* p6 = p5 + 9437184;
  float* diff96 = p6;                             // 73,728
  float* iMap   = diff96 + 73728;                 // 294,912
  float* dMap   = iMap + 294912;                  // 294,912
  float* scaleM = dMap + 294912;                  // 294,912
  float* pA = scaleM + 294912;                    // 10 x 64 floats
  float* A_up = pA;        float* B_up = pA + 64;
  float* A_c2 = pA + 128;  float* B_c2 = pA + 192;
  float* A_d1 = pA + 256;  float* B_d1 = pA + 320;
  float* A_d2 = pA + 384;  float* B_d2 = pA + 448;
  float* A_d3 = pA + 512;  float* B_d3 = pA + 576;
  short* wf_up = (short*)(pA + 640);              // 401,408 shorts
  short* wf_c2 = wf_up + 401408;                  // 36,864
  short* wf_d1 = wf_c2 + 36864;                   // 73,728
  short* wf_d2 = wf_d1 + 73728;                   // 36,864
  short* wf_d3 = wf_d2 + 36864;                   // 36,864

  float* out0 = (float*)d_out;         // r   (8,64,192,192) fp32 NCHW
  float* out1 = out0 + SZ;             // map (8,1,192,192)

  // ---- prep: epilogue folds + weight fragments + NHWC converts
  epi_prep_k<<<1, 64, 0, stream>>>(b_up, g_up, be_up, m_up, v_up, nullptr, 1, A_up, B_up);
  epi_prep_k<<<1, 64, 0, stream>>>(b_c2, nullptr, nullptr, nullptr, nullptr, beta, 0, A_c2, B_c2);
  epi_prep_k<<<1, 64, 0, stream>>>(b_d1, g_d1, be_d1, m_d1, v_d1, nullptr, 1, A_d1, B_d1);
  epi_prep_k<<<1, 64, 0, stream>>>(b_d2, g_d2, be_d2, m_d2, v_d2, nullptr, 1, A_d2, B_d2);
  epi_prep_k<<<1, 64, 0, stream>>>(b_d3, g_d3, be_d3, m_d3, v_d3, nullptr, 1, A_d3, B_d3);
  frag_up_k<<<1568, 256, 0, stream>>>(W_up, wf_up);
  frag3_k<<<144, 256, 0, stream>>>(W_c2, wf_c2, 64, 0);
  frag3_k<<<144, 256, 0, stream>>>(W_d1, wf_d1, 128, 0);
  frag3_k<<<144, 256, 0, stream>>>(W_d1, wf_d1 + 36864, 128, 64);
  frag3_k<<<144, 256, 0, stream>>>(W_d2, wf_d2, 64, 0);
  frag3_k<<<144, 256, 0, stream>>>(W_d3, wf_d3, 64, 0);
  to_nhwc_k<<<9216, 256, 0, stream>>>(x, xh, 8, 36864, 2359296);
  to_nhwc_k<<<4608, 256, 0, stream>>>(small_x, sxh, 16, 9216, 1179648);

  // ---- up path
  conv_up_h_k<<<1152, 256, 0, stream>>>(sxh, wf_up, partU);
  reduce_up_k<<<2304, 256, 0, stream>>>(partU, A_up, B_up, t0h);
  up2h_k<<<9216, 256, 0, stream>>>(t0h, smallh);

  // ---- uncertainty maps
  pools_h_k<<<288, 256, 0, stream>>>(smallh, xh, diff96);
  up2_k<true><<<1152, 256, 0, stream>>>(in_map, iMap, 8 * 192 * 192);
  up2_k<true><<<1152, 256, 0, stream>>>(diff96, dMap, 8 * 192 * 192);
  scale_k<<<1152, 256, 0, stream>>>(iMap, dMap, scaleM);

  // ---- conv chain (MFMA, NHWC bf16)
  conv3h_k<false, true, false, false><<<1152, 256, 0, stream>>>(
      xh, nullptr, wf_c2, A_c2, B_c2, scaleM, fnh, nullptr);
  conv3h_k<true, false, true, false><<<1152, 256, 0, stream>>>(
      smallh, fnh, wf_d1, A_d1, B_d1, nullptr, r1h, nullptr);
  conv3h_k<false, false, true, false><<<1152, 256, 0, stream>>>(
      r1h, nullptr, wf_d2, A_d2, B_d2, nullptr, r2h, nullptr);
  conv3h_k<false, false, true, true><<<1152, 256, 0, stream>>>(
      r2h, nullptr, wf_d3, A_d3, B_d3, nullptr, nullptr, out0);

  // ---- output head
  conv_out_part_k<<<2304, 128, 0, stream>>>(out0, W_out, partO);
  reduce_out_k<<<288, 256, 0, stream>>>(partO, b_out, out1);
}